// Round 1
// baseline (2540.598 us; speedup 1.0000x reference)
//
#include <hip/hip_runtime.h>
#include <math.h>

#define NN 100000
#define NE 1600000
#define F0 128
#define F1 64
#define F2 40

// ---------------- degree / dinv ----------------
__global__ __launch_bounds__(256) void k_deg_init(float* __restrict__ deg) {
    int i = blockIdx.x * 256 + threadIdx.x;
    if (i < NN) deg[i] = 1.0f;   // self-loop
}

__global__ __launch_bounds__(256) void k_deg_count(const int* __restrict__ dst,
                                                   float* __restrict__ deg) {
    int e = blockIdx.x * 256 + threadIdx.x;
    if (e < NE) atomicAdd(&deg[dst[e]], 1.0f);
}

__global__ __launch_bounds__(256) void k_dinv(float* __restrict__ deg) {
    int i = blockIdx.x * 256 + threadIdx.x;
    if (i < NN) deg[i] = rsqrtf(deg[i]);   // deg >= 1 always
}

// ---------------- GEMM1: hs = dinv[row] * (x @ W1), also init agg ----------------
// 32 rows/block, 64 cols, 256 threads: thread owns (colgroup j, 8 rows)
__global__ __launch_bounds__(256) void k_gemm1(const float* __restrict__ x,
                                               const float* __restrict__ W,
                                               const float* __restrict__ dinv,
                                               float* __restrict__ hs,
                                               float* __restrict__ agg) {
    __shared__ float wl[F0 * F1];   // 32 KB
    __shared__ float xl[32 * F0];   // 16 KB
    const int tid = threadIdx.x;
    const int row0 = blockIdx.x * 32;

    #pragma unroll
    for (int i = tid * 4; i < F0 * F1; i += 256 * 4)
        *(float4*)&wl[i] = *(const float4*)&W[i];
    #pragma unroll
    for (int i = tid * 4; i < 32 * F0; i += 256 * 4)
        *(float4*)&xl[i] = *(const float4*)&x[(size_t)row0 * F0 + i];
    __syncthreads();

    const int j = tid & 63;
    const int rg = tid >> 6;    // 0..3
    float acc[8];
    #pragma unroll
    for (int rr = 0; rr < 8; ++rr) acc[rr] = 0.0f;

    for (int k0 = 0; k0 < F0; k0 += 4) {
        float w0 = wl[(k0 + 0) * F1 + j];
        float w1 = wl[(k0 + 1) * F1 + j];
        float w2 = wl[(k0 + 2) * F1 + j];
        float w3 = wl[(k0 + 3) * F1 + j];
        #pragma unroll
        for (int rr = 0; rr < 8; ++rr) {
            float4 xv = *(float4*)&xl[(rg * 8 + rr) * F0 + k0];
            acc[rr] += xv.x * w0 + xv.y * w1 + xv.z * w2 + xv.w * w3;
        }
    }

    #pragma unroll
    for (int rr = 0; rr < 8; ++rr) {
        int r = row0 + rg * 8 + rr;   // 3125*32 == 100000 exactly
        float v = acc[rr] * dinv[r];
        hs[(size_t)r * F1 + j]  = v;
        agg[(size_t)r * F1 + j] = v;   // self-loop init
    }
}

// ---------------- agg1: agg[dst] += hs[src], 16 lanes x float4 per edge ----------------
__global__ __launch_bounds__(256) void k_agg1(const int* __restrict__ src,
                                              const int* __restrict__ dst,
                                              const float* __restrict__ hs,
                                              float* __restrict__ agg) {
    const int total = NE * 16;   // 25.6M
    for (int idx = blockIdx.x * 256 + threadIdx.x; idx < total;
         idx += gridDim.x * 256) {
        int e = idx >> 4;
        int g = idx & 15;
        int s = src[e];
        int d = dst[e];
        float4 v = *(const float4*)&hs[(size_t)s * F1 + g * 4];
        float* p = &agg[(size_t)d * F1 + g * 4];
        atomicAdd(p + 0, v.x);
        atomicAdd(p + 1, v.y);
        atomicAdd(p + 2, v.z);
        atomicAdd(p + 3, v.w);
    }
}

// ---------------- fin1: a = relu(dinv[i]*agg + b1) in place ----------------
__global__ __launch_bounds__(256) void k_fin1(float* __restrict__ agg,
                                              const float* __restrict__ dinv,
                                              const float* __restrict__ b) {
    int gid = blockIdx.x * 256 + threadIdx.x;   // one float4 each
    const int total = NN * F1 / 4;              // 1.6M
    if (gid >= total) return;
    int i  = gid >> 4;
    int j0 = (gid & 15) * 4;
    float dv = dinv[i];
    float4 v = ((float4*)agg)[gid];
    float4 bb = *(const float4*)&b[j0];
    v.x = fmaxf(dv * v.x + bb.x, 0.0f);
    v.y = fmaxf(dv * v.y + bb.y, 0.0f);
    v.z = fmaxf(dv * v.z + bb.z, 0.0f);
    v.w = fmaxf(dv * v.w + bb.w, 0.0f);
    ((float4*)agg)[gid] = v;
}

// ---------------- GEMM2: hs2 = dinv[row] * (a @ W2), also init d_out ----------------
// one row per thread; W2 (64x40) in LDS, broadcast reads
__global__ __launch_bounds__(256) void k_gemm2(const float* __restrict__ a,
                                               const float* __restrict__ W,
                                               const float* __restrict__ dinv,
                                               float* __restrict__ hs2,
                                               float* __restrict__ outInit) {
    __shared__ float wl[F1 * F2];   // 10 KB
    const int tid = threadIdx.x;
    for (int i = tid; i < F1 * F2; i += 256) wl[i] = W[i];
    __syncthreads();

    int r = blockIdx.x * 256 + tid;
    if (r >= NN) return;

    float acc[F2];
    #pragma unroll
    for (int j = 0; j < F2; ++j) acc[j] = 0.0f;

    const float* arow = a + (size_t)r * F1;
    for (int k0 = 0; k0 < F1; k0 += 4) {
        float4 av = *(const float4*)&arow[k0];
        #pragma unroll
        for (int j0 = 0; j0 < F2; j0 += 4) {
            float4 w0 = *(float4*)&wl[(k0 + 0) * F2 + j0];
            float4 w1 = *(float4*)&wl[(k0 + 1) * F2 + j0];
            float4 w2 = *(float4*)&wl[(k0 + 2) * F2 + j0];
            float4 w3 = *(float4*)&wl[(k0 + 3) * F2 + j0];
            acc[j0 + 0] += av.x * w0.x + av.y * w1.x + av.z * w2.x + av.w * w3.x;
            acc[j0 + 1] += av.x * w0.y + av.y * w1.y + av.z * w2.y + av.w * w3.y;
            acc[j0 + 2] += av.x * w0.z + av.y * w1.z + av.z * w2.z + av.w * w3.z;
            acc[j0 + 3] += av.x * w0.w + av.y * w1.w + av.z * w2.w + av.w * w3.w;
        }
    }

    float dv = dinv[r];
    #pragma unroll
    for (int j0 = 0; j0 < F2; j0 += 4) {
        float4 v;
        v.x = acc[j0 + 0] * dv;
        v.y = acc[j0 + 1] * dv;
        v.z = acc[j0 + 2] * dv;
        v.w = acc[j0 + 3] * dv;
        *(float4*)&hs2[(size_t)r * F2 + j0]    = v;
        *(float4*)&outInit[(size_t)r * F2 + j0] = v;   // self-loop init
    }
}

// ---------------- agg2: out[dst] += hs2[src], 10 lanes x float4 per edge ----------------
__global__ __launch_bounds__(256) void k_agg2(const int* __restrict__ src,
                                              const int* __restrict__ dst,
                                              const float* __restrict__ hs2,
                                              float* __restrict__ out) {
    const int total = NE * 10;   // 16M
    for (int idx = blockIdx.x * 256 + threadIdx.x; idx < total;
         idx += gridDim.x * 256) {
        int e = idx / 10;
        int g = idx - e * 10;
        int s = src[e];
        int d = dst[e];
        float4 v = *(const float4*)&hs2[(size_t)s * F2 + g * 4];
        float* p = &out[(size_t)d * F2 + g * 4];
        atomicAdd(p + 0, v.x);
        atomicAdd(p + 1, v.y);
        atomicAdd(p + 2, v.z);
        atomicAdd(p + 3, v.w);
    }
}

// ---------------- fin2: out = dinv[i]*out + b2 in place ----------------
__global__ __launch_bounds__(256) void k_fin2(float* __restrict__ out,
                                              const float* __restrict__ dinv,
                                              const float* __restrict__ b) {
    int gid = blockIdx.x * 256 + threadIdx.x;   // one float4 each
    const int total = NN * F2 / 4;              // 1M
    if (gid >= total) return;
    int i  = gid / 10;
    int q  = gid - i * 10;
    int j0 = q * 4;
    float dv = dinv[i];
    float4 v = ((float4*)out)[gid];
    float4 bb = *(const float4*)&b[j0];
    v.x = dv * v.x + bb.x;
    v.y = dv * v.y + bb.y;
    v.z = dv * v.z + bb.z;
    v.w = dv * v.w + bb.w;
    ((float4*)out)[gid] = v;
}

extern "C" void kernel_launch(void* const* d_in, const int* in_sizes, int n_in,
                              void* d_out, int out_size, void* d_ws, size_t ws_size,
                              hipStream_t stream) {
    const float* x  = (const float*)d_in[0];
    const int*   ei = (const int*)d_in[1];
    const float* W1 = (const float*)d_in[2];
    const float* b1 = (const float*)d_in[3];
    const float* W2 = (const float*)d_in[4];
    const float* b2 = (const float*)d_in[5];
    float* out = (float*)d_out;

    const int* src = ei;
    const int* dst = ei + NE;

    // workspace layout (floats): [dinv: NN pad->102400][bufA: NN*64][bufB: NN*64]
    float* dinv = (float*)d_ws;
    float* bufA = dinv + 102400;              // hs1 (N x 64), later hs2 (N x 40)
    float* bufB = bufA + (size_t)NN * F1;     // agg1, finalized a1 (N x 64)

    k_deg_init<<<(NN + 255) / 256, 256, 0, stream>>>(dinv);
    k_deg_count<<<(NE + 255) / 256, 256, 0, stream>>>(dst, dinv);
    k_dinv<<<(NN + 255) / 256, 256, 0, stream>>>(dinv);

    // layer 1
    k_gemm1<<<NN / 32, 256, 0, stream>>>(x, W1, dinv, bufA, bufB);
    k_agg1<<<4096, 256, 0, stream>>>(src, dst, bufA, bufB);
    k_fin1<<<(NN * F1 / 4 + 255) / 256, 256, 0, stream>>>(bufB, dinv, b1);

    // layer 2
    k_gemm2<<<(NN + 255) / 256, 256, 0, stream>>>(bufB, W2, dinv, bufA, out);
    k_agg2<<<4096, 256, 0, stream>>>(src, dst, bufA, out);
    k_fin2<<<(NN * F2 / 4 + 255) / 256, 256, 0, stream>>>(out, dinv, b2);
}

// Round 2
// 385.848 us; speedup vs baseline: 6.5844x; 6.5844x over previous
//
#include <hip/hip_runtime.h>
#include <math.h>

#define NN 100000
#define NE 1600000
#define F0 128
#define F1 64
#define F2 40
#define NPART 98   // ceil(NN / 1024)

// ---------------- CSR build ----------------
__global__ __launch_bounds__(256) void k_zero_int(int* __restrict__ p, int n) {
    int i = blockIdx.x * 256 + threadIdx.x;
    if (i < n) p[i] = 0;
}

__global__ __launch_bounds__(256) void k_hist(const int* __restrict__ dst,
                                              int* __restrict__ ideg) {
    int e = blockIdx.x * 256 + threadIdx.x;
    if (e < NE) atomicAdd(&ideg[dst[e]], 1);
}

__global__ __launch_bounds__(256) void k_dinv(const int* __restrict__ ideg,
                                              float* __restrict__ dinv) {
    int i = blockIdx.x * 256 + threadIdx.x;
    if (i < NN) dinv[i] = rsqrtf((float)(ideg[i] + 1));   // +1 self-loop
}

// block scans 1024 elements (256 thr x 4), writes exclusive prefix + block sum
__global__ __launch_bounds__(256) void k_scan1(const int* __restrict__ ideg,
                                               int* __restrict__ rs,
                                               int* __restrict__ part) {
    __shared__ int ls[256];
    int t = threadIdx.x, b = blockIdx.x;
    int base = b * 1024 + t * 4;
    int v0 = (base + 0 < NN) ? ideg[base + 0] : 0;
    int v1 = (base + 1 < NN) ? ideg[base + 1] : 0;
    int v2 = (base + 2 < NN) ? ideg[base + 2] : 0;
    int v3 = (base + 3 < NN) ? ideg[base + 3] : 0;
    int s = v0 + v1 + v2 + v3;
    ls[t] = s;
    __syncthreads();
    for (int off = 1; off < 256; off <<= 1) {
        int x = (t >= off) ? ls[t - off] : 0;
        __syncthreads();
        if (t >= off) ls[t] += x;
        __syncthreads();
    }
    int excl = ls[t] - s;
    if (t == 255) part[b] = ls[255];
    if (base + 0 < NN) rs[base + 0] = excl; excl += v0;
    if (base + 1 < NN) rs[base + 1] = excl; excl += v1;
    if (base + 2 < NN) rs[base + 2] = excl; excl += v2;
    if (base + 3 < NN) rs[base + 3] = excl;
}

__global__ void k_scan2(int* __restrict__ part) {
    if (threadIdx.x == 0 && blockIdx.x == 0) {
        int run = 0;
        for (int i = 0; i < NPART; ++i) { int v = part[i]; part[i] = run; run += v; }
    }
}

__global__ __launch_bounds__(256) void k_scan3(int* __restrict__ rs,
                                               const int* __restrict__ part,
                                               int* __restrict__ cur) {
    int i = blockIdx.x * 256 + threadIdx.x;
    if (i < NN) {
        int v = rs[i] + part[i >> 10];
        rs[i] = v;
        cur[i] = v;
    }
}

// scatter edges into CSR; afterwards cur[i] == rs[i] + deg[i] (segment end)
__global__ __launch_bounds__(256) void k_scatter(const int* __restrict__ src,
                                                 const int* __restrict__ dst,
                                                 int* __restrict__ cur,
                                                 int* __restrict__ csr) {
    int e = blockIdx.x * 256 + threadIdx.x;
    if (e < NE) {
        int pos = atomicAdd(&cur[dst[e]], 1);
        csr[pos] = src[e];
    }
}

// ---------------- GEMM1: hs = dinv[row] * (x @ W1) ----------------
__global__ __launch_bounds__(256) void k_gemm1(const float* __restrict__ x,
                                               const float* __restrict__ W,
                                               const float* __restrict__ dinv,
                                               float* __restrict__ hs) {
    __shared__ float wl[F0 * F1];   // 32 KB
    __shared__ float xl[32 * F0];   // 16 KB
    const int tid = threadIdx.x;
    const int row0 = blockIdx.x * 32;

    #pragma unroll
    for (int i = tid * 4; i < F0 * F1; i += 256 * 4)
        *(float4*)&wl[i] = *(const float4*)&W[i];
    #pragma unroll
    for (int i = tid * 4; i < 32 * F0; i += 256 * 4)
        *(float4*)&xl[i] = *(const float4*)&x[(size_t)row0 * F0 + i];
    __syncthreads();

    const int j = tid & 63;
    const int rg = tid >> 6;    // 0..3
    float acc[8];
    #pragma unroll
    for (int rr = 0; rr < 8; ++rr) acc[rr] = 0.0f;

    for (int k0 = 0; k0 < F0; k0 += 4) {
        float w0 = wl[(k0 + 0) * F1 + j];
        float w1 = wl[(k0 + 1) * F1 + j];
        float w2 = wl[(k0 + 2) * F1 + j];
        float w3 = wl[(k0 + 3) * F1 + j];
        #pragma unroll
        for (int rr = 0; rr < 8; ++rr) {
            float4 xv = *(float4*)&xl[(rg * 8 + rr) * F0 + k0];
            acc[rr] += xv.x * w0 + xv.y * w1 + xv.z * w2 + xv.w * w3;
        }
    }

    #pragma unroll
    for (int rr = 0; rr < 8; ++rr) {
        int r = row0 + rg * 8 + rr;   // 3125*32 == 100000 exactly
        hs[(size_t)r * F1 + j] = acc[rr] * dinv[r];
    }
}

// ---------------- gather1: a1 = relu(dinv*(hs[i] + sum_nbr hs[s]) + b1) ----------------
// 16-lane subgroup per node, float4 per lane; grid = NN*16/256 = 6250 exact
__global__ __launch_bounds__(256) void k_gather1(const int* __restrict__ rs,
                                                 const int* __restrict__ ce,
                                                 const int* __restrict__ csr,
                                                 const float* __restrict__ hs,
                                                 const float* __restrict__ dinv,
                                                 const float* __restrict__ b,
                                                 float* __restrict__ outp) {
    int t = blockIdx.x * 256 + threadIdx.x;
    int i = t >> 4;
    int g = t & 15;
    float4 acc = *(const float4*)&hs[(size_t)i * F1 + g * 4];   // self-loop
    int k = rs[i], end = ce[i];
    for (; k + 2 <= end; k += 2) {
        int s0 = csr[k], s1 = csr[k + 1];
        float4 v0 = *(const float4*)&hs[(size_t)s0 * F1 + g * 4];
        float4 v1 = *(const float4*)&hs[(size_t)s1 * F1 + g * 4];
        acc.x += v0.x + v1.x;
        acc.y += v0.y + v1.y;
        acc.z += v0.z + v1.z;
        acc.w += v0.w + v1.w;
    }
    if (k < end) {
        int s0 = csr[k];
        float4 v0 = *(const float4*)&hs[(size_t)s0 * F1 + g * 4];
        acc.x += v0.x; acc.y += v0.y; acc.z += v0.z; acc.w += v0.w;
    }
    float dv = dinv[i];
    float4 bb = *(const float4*)&b[g * 4];
    float4 r;
    r.x = fmaxf(fmaf(dv, acc.x, bb.x), 0.0f);
    r.y = fmaxf(fmaf(dv, acc.y, bb.y), 0.0f);
    r.z = fmaxf(fmaf(dv, acc.z, bb.z), 0.0f);
    r.w = fmaxf(fmaf(dv, acc.w, bb.w), 0.0f);
    *(float4*)&outp[(size_t)i * F1 + g * 4] = r;
}

// ---------------- GEMM2: hs2 = dinv[row] * (a1 @ W2) ----------------
__global__ __launch_bounds__(256) void k_gemm2(const float* __restrict__ a,
                                               const float* __restrict__ W,
                                               const float* __restrict__ dinv,
                                               float* __restrict__ hs2) {
    __shared__ float wl[F1 * F2];   // 10 KB
    const int tid = threadIdx.x;
    for (int i = tid; i < F1 * F2; i += 256) wl[i] = W[i];
    __syncthreads();

    int r = blockIdx.x * 256 + tid;
    if (r >= NN) return;

    float acc[F2];
    #pragma unroll
    for (int j = 0; j < F2; ++j) acc[j] = 0.0f;

    const float* arow = a + (size_t)r * F1;
    for (int k0 = 0; k0 < F1; k0 += 4) {
        float4 av = *(const float4*)&arow[k0];
        #pragma unroll
        for (int j0 = 0; j0 < F2; j0 += 4) {
            float4 w0 = *(float4*)&wl[(k0 + 0) * F2 + j0];
            float4 w1 = *(float4*)&wl[(k0 + 1) * F2 + j0];
            float4 w2 = *(float4*)&wl[(k0 + 2) * F2 + j0];
            float4 w3 = *(float4*)&wl[(k0 + 3) * F2 + j0];
            acc[j0 + 0] += av.x * w0.x + av.y * w1.x + av.z * w2.x + av.w * w3.x;
            acc[j0 + 1] += av.x * w0.y + av.y * w1.y + av.z * w2.y + av.w * w3.y;
            acc[j0 + 2] += av.x * w0.z + av.y * w1.z + av.z * w2.z + av.w * w3.z;
            acc[j0 + 3] += av.x * w0.w + av.y * w1.w + av.z * w2.w + av.w * w3.w;
        }
    }

    float dv = dinv[r];
    #pragma unroll
    for (int j0 = 0; j0 < F2; j0 += 4) {
        float4 v;
        v.x = acc[j0 + 0] * dv;
        v.y = acc[j0 + 1] * dv;
        v.z = acc[j0 + 2] * dv;
        v.w = acc[j0 + 3] * dv;
        *(float4*)&hs2[(size_t)r * F2 + j0] = v;
    }
}

// ---------------- gather2: out = dinv*(hs2[i] + sum_nbr hs2[s]) + b2 ----------------
// 16-lane subgroup per node, lanes g<10 active (F2 = 40 = 10 x float4)
__global__ __launch_bounds__(256) void k_gather2(const int* __restrict__ rs,
                                                 const int* __restrict__ ce,
                                                 const int* __restrict__ csr,
                                                 const float* __restrict__ hs2,
                                                 const float* __restrict__ dinv,
                                                 const float* __restrict__ b,
                                                 float* __restrict__ outp) {
    int t = blockIdx.x * 256 + threadIdx.x;
    int i = t >> 4;
    int g = t & 15;
    if (g >= 10) return;
    float4 acc = *(const float4*)&hs2[(size_t)i * F2 + g * 4];   // self-loop
    int k = rs[i], end = ce[i];
    for (; k + 2 <= end; k += 2) {
        int s0 = csr[k], s1 = csr[k + 1];
        float4 v0 = *(const float4*)&hs2[(size_t)s0 * F2 + g * 4];
        float4 v1 = *(const float4*)&hs2[(size_t)s1 * F2 + g * 4];
        acc.x += v0.x + v1.x;
        acc.y += v0.y + v1.y;
        acc.z += v0.z + v1.z;
        acc.w += v0.w + v1.w;
    }
    if (k < end) {
        int s0 = csr[k];
        float4 v0 = *(const float4*)&hs2[(size_t)s0 * F2 + g * 4];
        acc.x += v0.x; acc.y += v0.y; acc.z += v0.z; acc.w += v0.w;
    }
    float dv = dinv[i];
    float4 bb = *(const float4*)&b[g * 4];
    float4 r;
    r.x = fmaf(dv, acc.x, bb.x);
    r.y = fmaf(dv, acc.y, bb.y);
    r.z = fmaf(dv, acc.z, bb.z);
    r.w = fmaf(dv, acc.w, bb.w);
    *(float4*)&outp[(size_t)i * F2 + g * 4] = r;
}

extern "C" void kernel_launch(void* const* d_in, const int* in_sizes, int n_in,
                              void* d_out, int out_size, void* d_ws, size_t ws_size,
                              hipStream_t stream) {
    const float* x  = (const float*)d_in[0];
    const int*   ei = (const int*)d_in[1];
    const float* b1 = (const float*)d_in[3];
    const float* W1 = (const float*)d_in[2];
    const float* W2 = (const float*)d_in[4];
    const float* b2 = (const float*)d_in[5];
    float* out = (float*)d_out;

    const int* src = ei;
    const int* dst = ei + NE;

    // workspace layout in 4-byte units:
    // [dinv 102400][ideg 102400][rs 102400][cur 102400][part 1024]
    // [csr 1.6M][bufA 6.4M][bufB 6.4M]  total ~58.9 MB
    float* dinv = (float*)d_ws;
    int*   ideg = (int*)d_ws + 102400;
    int*   rs   = (int*)d_ws + 204800;
    int*   cur  = (int*)d_ws + 307200;
    int*   part = (int*)d_ws + 409600;
    int*   csr  = (int*)d_ws + 410624;
    float* bufA = (float*)d_ws + 410624 + NE;
    float* bufB = bufA + (size_t)NN * F1;

    // CSR build (reused by both layers)
    k_zero_int<<<(NN + 255) / 256, 256, 0, stream>>>(ideg, NN);
    k_hist<<<(NE + 255) / 256, 256, 0, stream>>>(dst, ideg);
    k_dinv<<<(NN + 255) / 256, 256, 0, stream>>>(ideg, dinv);
    k_scan1<<<NPART, 256, 0, stream>>>(ideg, rs, part);
    k_scan2<<<1, 64, 0, stream>>>(part);
    k_scan3<<<(NN + 255) / 256, 256, 0, stream>>>(rs, part, cur);
    k_scatter<<<(NE + 255) / 256, 256, 0, stream>>>(src, dst, cur, csr);

    // layer 1
    k_gemm1<<<NN / 32, 256, 0, stream>>>(x, W1, dinv, bufA);
    k_gather1<<<NN * 16 / 256, 256, 0, stream>>>(rs, cur, csr, bufA, dinv, b1, bufB);

    // layer 2
    k_gemm2<<<(NN + 255) / 256, 256, 0, stream>>>(bufB, W2, dinv, bufA);
    k_gather2<<<NN * 16 / 256, 256, 0, stream>>>(rs, cur, csr, bufA, dinv, b2, out);
}

// Round 3
// 339.369 us; speedup vs baseline: 7.4862x; 1.1370x over previous
//
#include <hip/hip_runtime.h>
#include <math.h>

#define NN 100000
#define NE 1600000
#define F0 128
#define F1 64
#define F2 40
#define NPART 98      // ceil(NN / 1024)
#define NXCD 8
#define RANGE 12500   // NN / NXCD

// ---------------- CSR build ----------------
__global__ __launch_bounds__(256) void k_zero_int(int* __restrict__ p, int n) {
    int i = blockIdx.x * 256 + threadIdx.x;
    if (i < n) p[i] = 0;
}

__global__ __launch_bounds__(256) void k_hist(const int* __restrict__ dst,
                                              int* __restrict__ ideg) {
    int e = blockIdx.x * 256 + threadIdx.x;
    if (e < NE) atomicAdd(&ideg[dst[e]], 1);
}

__global__ __launch_bounds__(256) void k_dinv(const int* __restrict__ ideg,
                                              float* __restrict__ dinv) {
    int i = blockIdx.x * 256 + threadIdx.x;
    if (i < NN) dinv[i] = rsqrtf((float)(ideg[i] + 1));   // +1 self-loop
}

// block scans 1024 elements (256 thr x 4), writes exclusive prefix + block sum
__global__ __launch_bounds__(256) void k_scan1(const int* __restrict__ ideg,
                                               int* __restrict__ rs,
                                               int* __restrict__ part) {
    __shared__ int ls[256];
    int t = threadIdx.x, b = blockIdx.x;
    int base = b * 1024 + t * 4;
    int v0 = (base + 0 < NN) ? ideg[base + 0] : 0;
    int v1 = (base + 1 < NN) ? ideg[base + 1] : 0;
    int v2 = (base + 2 < NN) ? ideg[base + 2] : 0;
    int v3 = (base + 3 < NN) ? ideg[base + 3] : 0;
    int s = v0 + v1 + v2 + v3;
    ls[t] = s;
    __syncthreads();
    for (int off = 1; off < 256; off <<= 1) {
        int x = (t >= off) ? ls[t - off] : 0;
        __syncthreads();
        if (t >= off) ls[t] += x;
        __syncthreads();
    }
    int excl = ls[t] - s;
    if (t == 255) part[b] = ls[255];
    if (base + 0 < NN) rs[base + 0] = excl; excl += v0;
    if (base + 1 < NN) rs[base + 1] = excl; excl += v1;
    if (base + 2 < NN) rs[base + 2] = excl; excl += v2;
    if (base + 3 < NN) rs[base + 3] = excl;
}

__global__ void k_scan2(int* __restrict__ part) {
    if (threadIdx.x == 0 && blockIdx.x == 0) {
        int run = 0;
        for (int i = 0; i < NPART; ++i) { int v = part[i]; part[i] = run; run += v; }
    }
}

__global__ __launch_bounds__(256) void k_scan3(int* __restrict__ rs,
                                               const int* __restrict__ part,
                                               int* __restrict__ cur) {
    int i = blockIdx.x * 256 + threadIdx.x;
    if (i < NN) {
        int v = rs[i] + part[i >> 10];
        rs[i] = v;
        cur[i] = v;
    }
}

// XCD-partitioned scatter: block b handles dst range [(b&7)*RANGE, +RANGE).
// Round-robin block->XCD dispatch makes each XCD's csr slice L2-local, so
// csr lines accumulate all 16 entries before write-back (dense writes).
// Correct regardless of the actual block->XCD mapping (ranges partition nodes).
__global__ __launch_bounds__(256) void k_scatter(const int* __restrict__ src,
                                                 const int* __restrict__ dst,
                                                 int* __restrict__ cur,
                                                 int* __restrict__ csr) {
    const int xcd = blockIdx.x & 7;
    const int j   = blockIdx.x >> 3;
    const int nj  = gridDim.x >> 3;
    const int lo = xcd * RANGE, hi = lo + RANGE;
    for (int e = j * 256 + threadIdx.x; e < NE; e += nj * 256) {
        int d = dst[e];
        if (d >= lo && d < hi) {
            int pos = atomicAdd(&cur[d], 1);
            csr[pos] = src[e];
        }
    }
}

// ---------------- GEMM1: hs = dinv[row] * (x @ W1) ----------------
__global__ __launch_bounds__(256) void k_gemm1(const float* __restrict__ x,
                                               const float* __restrict__ W,
                                               const float* __restrict__ dinv,
                                               float* __restrict__ hs) {
    __shared__ float wl[F0 * F1];   // 32 KB
    __shared__ float xl[32 * F0];   // 16 KB
    const int tid = threadIdx.x;
    const int row0 = blockIdx.x * 32;

    #pragma unroll
    for (int i = tid * 4; i < F0 * F1; i += 256 * 4)
        *(float4*)&wl[i] = *(const float4*)&W[i];
    #pragma unroll
    for (int i = tid * 4; i < 32 * F0; i += 256 * 4)
        *(float4*)&xl[i] = *(const float4*)&x[(size_t)row0 * F0 + i];
    __syncthreads();

    const int j = tid & 63;
    const int rg = tid >> 6;    // 0..3
    float acc[8];
    #pragma unroll
    for (int rr = 0; rr < 8; ++rr) acc[rr] = 0.0f;

    for (int k0 = 0; k0 < F0; k0 += 4) {
        float w0 = wl[(k0 + 0) * F1 + j];
        float w1 = wl[(k0 + 1) * F1 + j];
        float w2 = wl[(k0 + 2) * F1 + j];
        float w3 = wl[(k0 + 3) * F1 + j];
        #pragma unroll
        for (int rr = 0; rr < 8; ++rr) {
            float4 xv = *(float4*)&xl[(rg * 8 + rr) * F0 + k0];
            acc[rr] += xv.x * w0 + xv.y * w1 + xv.z * w2 + xv.w * w3;
        }
    }

    #pragma unroll
    for (int rr = 0; rr < 8; ++rr) {
        int r = row0 + rg * 8 + rr;   // 3125*32 == 100000 exactly
        hs[(size_t)r * F1 + j] = acc[rr] * dinv[r];
    }
}

// ---------------- gather1: a1 = relu(dinv*(hs[i] + sum_nbr hs[s]) + b1) ----------------
// 16-lane subgroup per node, float4 per lane; grid = NN*16/256 = 6250 exact
__global__ __launch_bounds__(256) void k_gather1(const int* __restrict__ rs,
                                                 const int* __restrict__ ce,
                                                 const int* __restrict__ csr,
                                                 const float* __restrict__ hs,
                                                 const float* __restrict__ dinv,
                                                 const float* __restrict__ b,
                                                 float* __restrict__ outp) {
    int t = blockIdx.x * 256 + threadIdx.x;
    int i = t >> 4;
    int g = t & 15;
    float4 acc = *(const float4*)&hs[(size_t)i * F1 + g * 4];   // self-loop
    int k = rs[i], end = ce[i];
    for (; k + 2 <= end; k += 2) {
        int s0 = csr[k], s1 = csr[k + 1];
        float4 v0 = *(const float4*)&hs[(size_t)s0 * F1 + g * 4];
        float4 v1 = *(const float4*)&hs[(size_t)s1 * F1 + g * 4];
        acc.x += v0.x + v1.x;
        acc.y += v0.y + v1.y;
        acc.z += v0.z + v1.z;
        acc.w += v0.w + v1.w;
    }
    if (k < end) {
        int s0 = csr[k];
        float4 v0 = *(const float4*)&hs[(size_t)s0 * F1 + g * 4];
        acc.x += v0.x; acc.y += v0.y; acc.z += v0.z; acc.w += v0.w;
    }
    float dv = dinv[i];
    float4 bb = *(const float4*)&b[g * 4];
    float4 r;
    r.x = fmaxf(fmaf(dv, acc.x, bb.x), 0.0f);
    r.y = fmaxf(fmaf(dv, acc.y, bb.y), 0.0f);
    r.z = fmaxf(fmaf(dv, acc.z, bb.z), 0.0f);
    r.w = fmaxf(fmaf(dv, acc.w, bb.w), 0.0f);
    *(float4*)&outp[(size_t)i * F1 + g * 4] = r;
}

// ---------------- GEMM2: hs2 = dinv[row] * (a1 @ W2) ----------------
__global__ __launch_bounds__(256) void k_gemm2(const float* __restrict__ a,
                                               const float* __restrict__ W,
                                               const float* __restrict__ dinv,
                                               float* __restrict__ hs2) {
    __shared__ float wl[F1 * F2];   // 10 KB
    const int tid = threadIdx.x;
    for (int i = tid; i < F1 * F2; i += 256) wl[i] = W[i];
    __syncthreads();

    int r = blockIdx.x * 256 + tid;
    if (r >= NN) return;

    float acc[F2];
    #pragma unroll
    for (int j = 0; j < F2; ++j) acc[j] = 0.0f;

    const float* arow = a + (size_t)r * F1;
    for (int k0 = 0; k0 < F1; k0 += 4) {
        float4 av = *(const float4*)&arow[k0];
        #pragma unroll
        for (int j0 = 0; j0 < F2; j0 += 4) {
            float4 w0 = *(float4*)&wl[(k0 + 0) * F2 + j0];
            float4 w1 = *(float4*)&wl[(k0 + 1) * F2 + j0];
            float4 w2 = *(float4*)&wl[(k0 + 2) * F2 + j0];
            float4 w3 = *(float4*)&wl[(k0 + 3) * F2 + j0];
            acc[j0 + 0] += av.x * w0.x + av.y * w1.x + av.z * w2.x + av.w * w3.x;
            acc[j0 + 1] += av.x * w0.y + av.y * w1.y + av.z * w2.y + av.w * w3.y;
            acc[j0 + 2] += av.x * w0.z + av.y * w1.z + av.z * w2.z + av.w * w3.z;
            acc[j0 + 3] += av.x * w0.w + av.y * w1.w + av.z * w2.w + av.w * w3.w;
        }
    }

    float dv = dinv[r];
    #pragma unroll
    for (int j0 = 0; j0 < F2; j0 += 4) {
        float4 v;
        v.x = acc[j0 + 0] * dv;
        v.y = acc[j0 + 1] * dv;
        v.z = acc[j0 + 2] * dv;
        v.w = acc[j0 + 3] * dv;
        *(float4*)&hs2[(size_t)r * F2 + j0] = v;
    }
}

// ---------------- gather2: out = dinv*(hs2[i] + sum_nbr hs2[s]) + b2 ----------------
// 10 lanes per node (F2 = 40 = 10 x float4), 320-thread blocks = 32 nodes/block
__global__ __launch_bounds__(320) void k_gather2(const int* __restrict__ rs,
                                                 const int* __restrict__ ce,
                                                 const int* __restrict__ csr,
                                                 const float* __restrict__ hs2,
                                                 const float* __restrict__ dinv,
                                                 const float* __restrict__ b,
                                                 float* __restrict__ outp) {
    int t = blockIdx.x * 320 + threadIdx.x;   // t < 1,000,000 exact
    int i = t / 10;
    int g = t - i * 10;
    float4 acc = *(const float4*)&hs2[(size_t)i * F2 + g * 4];   // self-loop
    int k = rs[i], end = ce[i];
    for (; k + 2 <= end; k += 2) {
        int s0 = csr[k], s1 = csr[k + 1];
        float4 v0 = *(const float4*)&hs2[(size_t)s0 * F2 + g * 4];
        float4 v1 = *(const float4*)&hs2[(size_t)s1 * F2 + g * 4];
        acc.x += v0.x + v1.x;
        acc.y += v0.y + v1.y;
        acc.z += v0.z + v1.z;
        acc.w += v0.w + v1.w;
    }
    if (k < end) {
        int s0 = csr[k];
        float4 v0 = *(const float4*)&hs2[(size_t)s0 * F2 + g * 4];
        acc.x += v0.x; acc.y += v0.y; acc.z += v0.z; acc.w += v0.w;
    }
    float dv = dinv[i];
    float4 bb = *(const float4*)&b[g * 4];
    float4 r;
    r.x = fmaf(dv, acc.x, bb.x);
    r.y = fmaf(dv, acc.y, bb.y);
    r.z = fmaf(dv, acc.z, bb.z);
    r.w = fmaf(dv, acc.w, bb.w);
    *(float4*)&outp[(size_t)i * F2 + g * 4] = r;
}

extern "C" void kernel_launch(void* const* d_in, const int* in_sizes, int n_in,
                              void* d_out, int out_size, void* d_ws, size_t ws_size,
                              hipStream_t stream) {
    const float* x  = (const float*)d_in[0];
    const int*   ei = (const int*)d_in[1];
    const float* W1 = (const float*)d_in[2];
    const float* b1 = (const float*)d_in[3];
    const float* W2 = (const float*)d_in[4];
    const float* b2 = (const float*)d_in[5];
    float* out = (float*)d_out;

    const int* src = ei;
    const int* dst = ei + NE;

    // workspace layout in 4-byte units:
    // [dinv 102400][ideg 102400][rs 102400][cur 102400][part 1024]
    // [csr 1.6M][bufA 6.4M][bufB 6.4M]  total ~58.9 MB
    float* dinv = (float*)d_ws;
    int*   ideg = (int*)d_ws + 102400;
    int*   rs   = (int*)d_ws + 204800;
    int*   cur  = (int*)d_ws + 307200;
    int*   part = (int*)d_ws + 409600;
    int*   csr  = (int*)d_ws + 410624;
    float* bufA = (float*)d_ws + 410624 + NE;
    float* bufB = bufA + (size_t)NN * F1;

    // CSR build (reused by both layers)
    k_zero_int<<<(NN + 255) / 256, 256, 0, stream>>>(ideg, NN);
    k_hist<<<(NE + 255) / 256, 256, 0, stream>>>(dst, ideg);
    k_dinv<<<(NN + 255) / 256, 256, 0, stream>>>(ideg, dinv);
    k_scan1<<<NPART, 256, 0, stream>>>(ideg, rs, part);
    k_scan2<<<1, 64, 0, stream>>>(part);
    k_scan3<<<(NN + 255) / 256, 256, 0, stream>>>(rs, part, cur);
    k_scatter<<<1024, 256, 0, stream>>>(src, dst, cur, csr);

    // layer 1
    k_gemm1<<<NN / 32, 256, 0, stream>>>(x, W1, dinv, bufA);
    k_gather1<<<NN * 16 / 256, 256, 0, stream>>>(rs, cur, csr, bufA, dinv, b1, bufB);

    // layer 2
    k_gemm2<<<(NN + 255) / 256, 256, 0, stream>>>(bufB, W2, dinv, bufA);
    k_gather2<<<NN / 32, 320, 0, stream>>>(rs, cur, csr, bufA, dinv, b2, out);
}

// Round 4
// 335.853 us; speedup vs baseline: 7.5646x; 1.0105x over previous
//
#include <hip/hip_runtime.h>
#include <math.h>

#define NN 100000
#define NE 1600000
#define F0 128
#define F1 64
#define F2 40
#define RANGE 12500        // NN / 8
#define CHUNK 1563         // ceil(NE / 1024)
#define CAP 220000         // bucket capacity (mean 200k, std ~420)
#define SUBSZ 391          // nodes per sub-range (32*391 >= 12500)
#define STASH 8192         // per-sub-range edge stash (mean 6250, std ~79)

// ---------------- zero counters ----------------
__global__ void k_zero9(int* __restrict__ p) {
    if (threadIdx.x < 9) p[threadIdx.x] = 0;   // bucketCnt[8] + gCursor
}

// ---------------- phase A: 8-bucket partition by dst range ----------------
// pack = (loc << 17) | src,  loc = dst - range*12500 (<2^14), src < 2^17
__global__ __launch_bounds__(256) void k_part(const int* __restrict__ src,
                                              const int* __restrict__ dst,
                                              int* __restrict__ bucketCnt,
                                              unsigned* __restrict__ bucket) {
    __shared__ int cnt[8], base[8], cur[8];
    const int tid = threadIdx.x;
    if (tid < 8) cnt[tid] = 0;
    __syncthreads();
    const int e0 = blockIdx.x * CHUNK;
    const int e1 = (e0 + CHUNK < NE) ? e0 + CHUNK : NE;
    for (int e = e0 + tid; e < e1; e += 256) {
        int r = dst[e] / RANGE;
        atomicAdd(&cnt[r], 1);
    }
    __syncthreads();
    if (tid < 8) {
        base[tid] = atomicAdd(&bucketCnt[tid], cnt[tid]);
        cur[tid] = 0;
    }
    __syncthreads();
    for (int e = e0 + tid; e < e1; e += 256) {
        int d = dst[e];
        int s = src[e];
        int r = d / RANGE;
        int loc = d - r * RANGE;
        int p = base[r] + atomicAdd(&cur[r], 1);
        bucket[(size_t)r * CAP + p] = ((unsigned)loc << 17) | (unsigned)s;
    }
}

// ---------------- phase B: per-sub-range CSR segment build ----------------
// block = (range r = blk&7, sub = blk>>3); streams bucket r from XCD-local L2,
// builds rs/ce/csr/dinv for its <=391 nodes entirely in LDS; ONE global atomic.
__global__ __launch_bounds__(512) void k_build(const int* __restrict__ bucketCnt,
                                               const unsigned* __restrict__ bucket,
                                               int* __restrict__ gCursor,
                                               int* __restrict__ rs,
                                               int* __restrict__ ce,
                                               int* __restrict__ csr,
                                               float* __restrict__ dinv) {
    __shared__ unsigned stash[STASH];
    __shared__ int cnt[512];
    __shared__ int sc[512];
    __shared__ int lcnt, sh_base;

    const int tid = threadIdx.x;
    const int r = blockIdx.x & 7;
    const int sub = blockIdx.x >> 3;
    const int n0loc = sub * SUBSZ;
    const int nn = (RANGE - n0loc < SUBSZ) ? (RANGE - n0loc) : SUBSZ;
    const int n0 = r * RANGE + n0loc;

    cnt[tid] = 0;
    if (tid == 0) lcnt = 0;
    __syncthreads();

    // scan bucket r, stash owned edges, count per node
    const int cntR = bucketCnt[r];
    const unsigned* bk = bucket + (size_t)r * CAP;
    for (int idx = tid; idx < cntR; idx += 512) {
        unsigned p = bk[idx];
        int l2 = (int)(p >> 17) - n0loc;
        if ((unsigned)l2 < (unsigned)nn) {
            int pos = atomicAdd(&lcnt, 1);
            if (pos < STASH)
                stash[pos] = ((unsigned)l2 << 17) | (p & 0x1FFFFu);
            atomicAdd(&cnt[l2], 1);
        }
    }
    __syncthreads();

    // inclusive scan of cnt[0..512) into sc
    sc[tid] = cnt[tid];
    __syncthreads();
    for (int off = 1; off < 512; off <<= 1) {
        int v = (tid >= off) ? sc[tid - off] : 0;
        __syncthreads();
        sc[tid] += v;
        __syncthreads();
    }

    int T = sc[nn - 1];            // total owned edges (all threads read)
    if (tid == 0) sh_base = atomicAdd(gCursor, T);
    __syncthreads();
    const int base = sh_base;

    if (tid < nn) {
        int c = cnt[tid];
        int excl = sc[tid] - c;
        rs[n0 + tid] = base + excl;
        ce[n0 + tid] = base + sc[tid];
        dinv[n0 + tid] = rsqrtf((float)(c + 1));   // +1 self-loop
        sc[tid] = excl;
    }
    cnt[tid] = 0;                  // reuse as placement cursor
    __syncthreads();

    const int nst = (T < STASH) ? T : STASH;
    for (int idx = tid; idx < nst; idx += 512) {
        unsigned p = stash[idx];
        int l2 = (int)(p >> 17);
        int ofs = atomicAdd(&cnt[l2], 1);
        csr[base + sc[l2] + ofs] = (int)(p & 0x1FFFFu);
    }
}

// ---------------- GEMM1: hs = dinv[row] * (x @ W1) ----------------
__global__ __launch_bounds__(256) void k_gemm1(const float* __restrict__ x,
                                               const float* __restrict__ W,
                                               const float* __restrict__ dinv,
                                               float* __restrict__ hs) {
    __shared__ float wl[F0 * F1];   // 32 KB
    __shared__ float xl[32 * F0];   // 16 KB
    const int tid = threadIdx.x;
    const int row0 = blockIdx.x * 32;

    #pragma unroll
    for (int i = tid * 4; i < F0 * F1; i += 256 * 4)
        *(float4*)&wl[i] = *(const float4*)&W[i];
    #pragma unroll
    for (int i = tid * 4; i < 32 * F0; i += 256 * 4)
        *(float4*)&xl[i] = *(const float4*)&x[(size_t)row0 * F0 + i];
    __syncthreads();

    const int j = tid & 63;
    const int rg = tid >> 6;    // 0..3
    float acc[8];
    #pragma unroll
    for (int rr = 0; rr < 8; ++rr) acc[rr] = 0.0f;

    for (int k0 = 0; k0 < F0; k0 += 4) {
        float w0 = wl[(k0 + 0) * F1 + j];
        float w1 = wl[(k0 + 1) * F1 + j];
        float w2 = wl[(k0 + 2) * F1 + j];
        float w3 = wl[(k0 + 3) * F1 + j];
        #pragma unroll
        for (int rr = 0; rr < 8; ++rr) {
            float4 xv = *(float4*)&xl[(rg * 8 + rr) * F0 + k0];
            acc[rr] += xv.x * w0 + xv.y * w1 + xv.z * w2 + xv.w * w3;
        }
    }

    #pragma unroll
    for (int rr = 0; rr < 8; ++rr) {
        int r = row0 + rg * 8 + rr;   // 3125*32 == 100000 exactly
        hs[(size_t)r * F1 + j] = acc[rr] * dinv[r];
    }
}

// ---------------- gather1: a1 = relu(dinv*(hs[i] + sum_nbr hs[s]) + b1) ----------------
// 16-lane subgroup per node, float4 per lane; unroll-4 for MLP
__global__ __launch_bounds__(256) void k_gather1(const int* __restrict__ rs,
                                                 const int* __restrict__ ce,
                                                 const int* __restrict__ csr,
                                                 const float* __restrict__ hs,
                                                 const float* __restrict__ dinv,
                                                 const float* __restrict__ b,
                                                 float* __restrict__ outp) {
    int t = blockIdx.x * 256 + threadIdx.x;
    int i = t >> 4;
    int g = t & 15;
    float4 acc = *(const float4*)&hs[(size_t)i * F1 + g * 4];   // self-loop
    int k = rs[i], end = ce[i];
    for (; k + 4 <= end; k += 4) {
        int s0 = csr[k], s1 = csr[k + 1], s2 = csr[k + 2], s3 = csr[k + 3];
        float4 v0 = *(const float4*)&hs[(size_t)s0 * F1 + g * 4];
        float4 v1 = *(const float4*)&hs[(size_t)s1 * F1 + g * 4];
        float4 v2 = *(const float4*)&hs[(size_t)s2 * F1 + g * 4];
        float4 v3 = *(const float4*)&hs[(size_t)s3 * F1 + g * 4];
        acc.x += (v0.x + v1.x) + (v2.x + v3.x);
        acc.y += (v0.y + v1.y) + (v2.y + v3.y);
        acc.z += (v0.z + v1.z) + (v2.z + v3.z);
        acc.w += (v0.w + v1.w) + (v2.w + v3.w);
    }
    for (; k < end; ++k) {
        int s0 = csr[k];
        float4 v0 = *(const float4*)&hs[(size_t)s0 * F1 + g * 4];
        acc.x += v0.x; acc.y += v0.y; acc.z += v0.z; acc.w += v0.w;
    }
    float dv = dinv[i];
    float4 bb = *(const float4*)&b[g * 4];
    float4 r;
    r.x = fmaxf(fmaf(dv, acc.x, bb.x), 0.0f);
    r.y = fmaxf(fmaf(dv, acc.y, bb.y), 0.0f);
    r.z = fmaxf(fmaf(dv, acc.z, bb.z), 0.0f);
    r.w = fmaxf(fmaf(dv, acc.w, bb.w), 0.0f);
    *(float4*)&outp[(size_t)i * F1 + g * 4] = r;
}

// ---------------- GEMM2: hs2 = dinv[row] * (a1 @ W2) ----------------
__global__ __launch_bounds__(256) void k_gemm2(const float* __restrict__ a,
                                               const float* __restrict__ W,
                                               const float* __restrict__ dinv,
                                               float* __restrict__ hs2) {
    __shared__ float wl[F1 * F2];   // 10 KB
    const int tid = threadIdx.x;
    for (int i = tid; i < F1 * F2; i += 256) wl[i] = W[i];
    __syncthreads();

    int r = blockIdx.x * 256 + tid;
    if (r >= NN) return;

    float acc[F2];
    #pragma unroll
    for (int j = 0; j < F2; ++j) acc[j] = 0.0f;

    const float* arow = a + (size_t)r * F1;
    for (int k0 = 0; k0 < F1; k0 += 4) {
        float4 av = *(const float4*)&arow[k0];
        #pragma unroll
        for (int j0 = 0; j0 < F2; j0 += 4) {
            float4 w0 = *(float4*)&wl[(k0 + 0) * F2 + j0];
            float4 w1 = *(float4*)&wl[(k0 + 1) * F2 + j0];
            float4 w2 = *(float4*)&wl[(k0 + 2) * F2 + j0];
            float4 w3 = *(float4*)&wl[(k0 + 3) * F2 + j0];
            acc[j0 + 0] += av.x * w0.x + av.y * w1.x + av.z * w2.x + av.w * w3.x;
            acc[j0 + 1] += av.x * w0.y + av.y * w1.y + av.z * w2.y + av.w * w3.y;
            acc[j0 + 2] += av.x * w0.z + av.y * w1.z + av.z * w2.z + av.w * w3.z;
            acc[j0 + 3] += av.x * w0.w + av.y * w1.w + av.z * w2.w + av.w * w3.w;
        }
    }

    float dv = dinv[r];
    #pragma unroll
    for (int j0 = 0; j0 < F2; j0 += 4) {
        float4 v;
        v.x = acc[j0 + 0] * dv;
        v.y = acc[j0 + 1] * dv;
        v.z = acc[j0 + 2] * dv;
        v.w = acc[j0 + 3] * dv;
        *(float4*)&hs2[(size_t)r * F2 + j0] = v;
    }
}

// ---------------- gather2: out = dinv*(hs2[i] + sum_nbr hs2[s]) + b2 ----------------
// 10 lanes per node (F2 = 40 = 10 x float4), 320-thread blocks = 32 nodes/block
__global__ __launch_bounds__(320) void k_gather2(const int* __restrict__ rs,
                                                 const int* __restrict__ ce,
                                                 const int* __restrict__ csr,
                                                 const float* __restrict__ hs2,
                                                 const float* __restrict__ dinv,
                                                 const float* __restrict__ b,
                                                 float* __restrict__ outp) {
    int t = blockIdx.x * 320 + threadIdx.x;   // t < 1,000,000 exact
    int i = t / 10;
    int g = t - i * 10;
    float4 acc = *(const float4*)&hs2[(size_t)i * F2 + g * 4];   // self-loop
    int k = rs[i], end = ce[i];
    for (; k + 4 <= end; k += 4) {
        int s0 = csr[k], s1 = csr[k + 1], s2 = csr[k + 2], s3 = csr[k + 3];
        float4 v0 = *(const float4*)&hs2[(size_t)s0 * F2 + g * 4];
        float4 v1 = *(const float4*)&hs2[(size_t)s1 * F2 + g * 4];
        float4 v2 = *(const float4*)&hs2[(size_t)s2 * F2 + g * 4];
        float4 v3 = *(const float4*)&hs2[(size_t)s3 * F2 + g * 4];
        acc.x += (v0.x + v1.x) + (v2.x + v3.x);
        acc.y += (v0.y + v1.y) + (v2.y + v3.y);
        acc.z += (v0.z + v1.z) + (v2.z + v3.z);
        acc.w += (v0.w + v1.w) + (v2.w + v3.w);
    }
    for (; k < end; ++k) {
        int s0 = csr[k];
        float4 v0 = *(const float4*)&hs2[(size_t)s0 * F2 + g * 4];
        acc.x += v0.x; acc.y += v0.y; acc.z += v0.z; acc.w += v0.w;
    }
    float dv = dinv[i];
    float4 bb = *(const float4*)&b[g * 4];
    float4 r;
    r.x = fmaf(dv, acc.x, bb.x);
    r.y = fmaf(dv, acc.y, bb.y);
    r.z = fmaf(dv, acc.z, bb.z);
    r.w = fmaf(dv, acc.w, bb.w);
    *(float4*)&outp[(size_t)i * F2 + g * 4] = r;
}

extern "C" void kernel_launch(void* const* d_in, const int* in_sizes, int n_in,
                              void* d_out, int out_size, void* d_ws, size_t ws_size,
                              hipStream_t stream) {
    const float* x  = (const float*)d_in[0];
    const int*   ei = (const int*)d_in[1];
    const float* W1 = (const float*)d_in[2];
    const float* b1 = (const float*)d_in[3];
    const float* W2 = (const float*)d_in[4];
    const float* b2 = (const float*)d_in[5];
    float* out = (float*)d_out;

    const int* src = ei;
    const int* dst = ei + NE;

    // workspace layout in 4-byte units (total ~58.8 MB):
    // [dinv 102400][rs 102400][ce 102400][bucketCnt 8 + gCursor 1, pad->1024]
    // [csr 1.6M][bufA 6.4M][bufB 6.4M]   (bucket aliases bufB: 1.76M used)
    float* dinv      = (float*)d_ws;
    int*   rs        = (int*)d_ws + 102400;
    int*   ce        = (int*)d_ws + 204800;
    int*   bucketCnt = (int*)d_ws + 307200;       // [0..7]=counts, [8]=gCursor
    int*   csr       = (int*)d_ws + 308224;
    float* bufA      = (float*)d_ws + 308224 + NE;
    float* bufB      = bufA + (size_t)NN * F1;
    unsigned* bucket = (unsigned*)bufB;           // consumed before bufB is written

    // CSR + dinv build (two passes, no per-edge global atomics)
    k_zero9<<<1, 64, 0, stream>>>(bucketCnt);
    k_part<<<1024, 256, 0, stream>>>(src, dst, bucketCnt, bucket);
    k_build<<<256, 512, 0, stream>>>(bucketCnt, bucket, bucketCnt + 8,
                                     rs, ce, csr, dinv);

    // layer 1
    k_gemm1<<<NN / 32, 256, 0, stream>>>(x, W1, dinv, bufA);
    k_gather1<<<NN * 16 / 256, 256, 0, stream>>>(rs, ce, csr, bufA, dinv, b1, bufB);

    // layer 2
    k_gemm2<<<(NN + 255) / 256, 256, 0, stream>>>(bufB, W2, dinv, bufA);
    k_gather2<<<NN / 32, 320, 0, stream>>>(rs, ce, csr, bufA, dinv, b2, out);
}

// Round 5
// 229.271 us; speedup vs baseline: 11.0812x; 1.4649x over previous
//
#include <hip/hip_runtime.h>
#include <math.h>

#define NN 100000
#define NE 1600000
#define F0 128
#define F1 64
#define F2 40
#define NB 256         // buckets = CSR-build blocks
#define BSZ 391        // nodes per bucket (391*256 = 100096 >= NN)
#define CAP2 8192      // bucket capacity (mean 6250, sigma 79 -> 24 sigma)
#define CHUNK 3125     // NE / 512 partition blocks

// ---------------- zero counters: bucketCnt[256] + gCursor ----------------
__global__ void k_zero(int* __restrict__ p) {
    if (threadIdx.x < NB + 1) p[threadIdx.x] = 0;
}

// ---------------- phase A: 256-bucket partition by dst sub-range ----------------
// pack = (loc << 17) | src,  loc = dst - b*BSZ (< 391 < 2^9), src < 2^17
__global__ __launch_bounds__(256) void k_part(const int* __restrict__ src,
                                              const int* __restrict__ dst,
                                              int* __restrict__ bucketCnt,
                                              unsigned* __restrict__ bucket) {
    __shared__ int cnt[NB], base[NB];
    const int tid = threadIdx.x;
    cnt[tid] = 0;
    __syncthreads();
    const int e0 = blockIdx.x * CHUNK;
    const int e1 = e0 + CHUNK;   // 512 * 3125 == NE exactly
    for (int e = e0 + tid; e < e1; e += 256)
        atomicAdd(&cnt[dst[e] / BSZ], 1);
    __syncthreads();
    base[tid] = atomicAdd(&bucketCnt[tid], cnt[tid]);
    cnt[tid] = 0;
    __syncthreads();
    for (int e = e0 + tid; e < e1; e += 256) {
        int d = dst[e];
        int b = d / BSZ;
        int loc = d - b * BSZ;
        int ofs = atomicAdd(&cnt[b], 1);
        bucket[(size_t)b * CAP2 + base[b] + ofs] = ((unsigned)loc << 17) | (unsigned)src[e];
    }
}

// ---------------- phase B: per-bucket CSR segment build ----------------
// block b owns nodes [b*BSZ, b*BSZ+nn); reads ONLY its own bucket (~6250 edges,
// L2-resident on the 2nd pass); one global atomic per block.
__global__ __launch_bounds__(512) void k_build(const int* __restrict__ bucketCnt,
                                               const unsigned* __restrict__ bucket,
                                               int* __restrict__ gCursor,
                                               int* __restrict__ rs,
                                               int* __restrict__ ce,
                                               int* __restrict__ csr,
                                               float* __restrict__ dinv) {
    __shared__ int cnt[512];
    __shared__ int sc[512];
    __shared__ int sh_base;

    const int tid = threadIdx.x;
    const int b = blockIdx.x;
    const int n0 = b * BSZ;
    const int nn = (NN - n0 < BSZ) ? (NN - n0) : BSZ;

    cnt[tid] = 0;
    __syncthreads();

    const int cntB = bucketCnt[b];
    const unsigned* bk = bucket + (size_t)b * CAP2;
    for (int idx = tid; idx < cntB; idx += 512)
        atomicAdd(&cnt[bk[idx] >> 17], 1);
    __syncthreads();

    // inclusive scan cnt -> sc
    sc[tid] = cnt[tid];
    __syncthreads();
    for (int off = 1; off < 512; off <<= 1) {
        int v = (tid >= off) ? sc[tid - off] : 0;
        __syncthreads();
        sc[tid] += v;
        __syncthreads();
    }

    const int T = sc[511];   // == total owned edges (cnt[i>=nn] are 0)
    if (tid == 0) sh_base = atomicAdd(gCursor, T);
    __syncthreads();
    const int base = sh_base;

    if (tid < nn) {
        int c = cnt[tid];
        int excl = sc[tid] - c;
        rs[n0 + tid] = base + excl;
        ce[n0 + tid] = base + sc[tid];
        dinv[n0 + tid] = rsqrtf((float)(c + 1));   // +1 self-loop
        sc[tid] = excl;                            // placement offsets
    }
    cnt[tid] = 0;                                  // reuse as cursor
    __syncthreads();

    for (int idx = tid; idx < cntB; idx += 512) {
        unsigned p = bk[idx];
        int l = (int)(p >> 17);
        int ofs = atomicAdd(&cnt[l], 1);
        csr[base + sc[l] + ofs] = (int)(p & 0x1FFFFu);
    }
}

// ---------------- GEMM1: hs = dinv[row] * (x @ W1) ----------------
__global__ __launch_bounds__(256) void k_gemm1(const float* __restrict__ x,
                                               const float* __restrict__ W,
                                               const float* __restrict__ dinv,
                                               float* __restrict__ hs) {
    __shared__ float wl[F0 * F1];   // 32 KB
    __shared__ float xl[32 * F0];   // 16 KB
    const int tid = threadIdx.x;
    const int row0 = blockIdx.x * 32;

    #pragma unroll
    for (int i = tid * 4; i < F0 * F1; i += 256 * 4)
        *(float4*)&wl[i] = *(const float4*)&W[i];
    #pragma unroll
    for (int i = tid * 4; i < 32 * F0; i += 256 * 4)
        *(float4*)&xl[i] = *(const float4*)&x[(size_t)row0 * F0 + i];
    __syncthreads();

    const int j = tid & 63;
    const int rg = tid >> 6;    // 0..3
    float acc[8];
    #pragma unroll
    for (int rr = 0; rr < 8; ++rr) acc[rr] = 0.0f;

    for (int k0 = 0; k0 < F0; k0 += 4) {
        float w0 = wl[(k0 + 0) * F1 + j];
        float w1 = wl[(k0 + 1) * F1 + j];
        float w2 = wl[(k0 + 2) * F1 + j];
        float w3 = wl[(k0 + 3) * F1 + j];
        #pragma unroll
        for (int rr = 0; rr < 8; ++rr) {
            float4 xv = *(float4*)&xl[(rg * 8 + rr) * F0 + k0];
            acc[rr] += xv.x * w0 + xv.y * w1 + xv.z * w2 + xv.w * w3;
        }
    }

    #pragma unroll
    for (int rr = 0; rr < 8; ++rr) {
        int r = row0 + rg * 8 + rr;   // 3125*32 == 100000 exactly
        hs[(size_t)r * F1 + j] = acc[rr] * dinv[r];
    }
}

// ---------------- gather1: a1 = relu(dinv*(hs[i] + sum_nbr hs[s]) + b1) ----------------
// 16-lane subgroup per node, float4 per lane; unroll-4 for MLP
__global__ __launch_bounds__(256) void k_gather1(const int* __restrict__ rs,
                                                 const int* __restrict__ ce,
                                                 const int* __restrict__ csr,
                                                 const float* __restrict__ hs,
                                                 const float* __restrict__ dinv,
                                                 const float* __restrict__ b,
                                                 float* __restrict__ outp) {
    int t = blockIdx.x * 256 + threadIdx.x;
    int i = t >> 4;
    int g = t & 15;
    float4 acc = *(const float4*)&hs[(size_t)i * F1 + g * 4];   // self-loop
    int k = rs[i], end = ce[i];
    for (; k + 4 <= end; k += 4) {
        int s0 = csr[k], s1 = csr[k + 1], s2 = csr[k + 2], s3 = csr[k + 3];
        float4 v0 = *(const float4*)&hs[(size_t)s0 * F1 + g * 4];
        float4 v1 = *(const float4*)&hs[(size_t)s1 * F1 + g * 4];
        float4 v2 = *(const float4*)&hs[(size_t)s2 * F1 + g * 4];
        float4 v3 = *(const float4*)&hs[(size_t)s3 * F1 + g * 4];
        acc.x += (v0.x + v1.x) + (v2.x + v3.x);
        acc.y += (v0.y + v1.y) + (v2.y + v3.y);
        acc.z += (v0.z + v1.z) + (v2.z + v3.z);
        acc.w += (v0.w + v1.w) + (v2.w + v3.w);
    }
    for (; k < end; ++k) {
        int s0 = csr[k];
        float4 v0 = *(const float4*)&hs[(size_t)s0 * F1 + g * 4];
        acc.x += v0.x; acc.y += v0.y; acc.z += v0.z; acc.w += v0.w;
    }
    float dv = dinv[i];
    float4 bb = *(const float4*)&b[g * 4];
    float4 r;
    r.x = fmaxf(fmaf(dv, acc.x, bb.x), 0.0f);
    r.y = fmaxf(fmaf(dv, acc.y, bb.y), 0.0f);
    r.z = fmaxf(fmaf(dv, acc.z, bb.z), 0.0f);
    r.w = fmaxf(fmaf(dv, acc.w, bb.w), 0.0f);
    *(float4*)&outp[(size_t)i * F1 + g * 4] = r;
}

// ---------------- GEMM2: hs2 = dinv[row] * (a1 @ W2) ----------------
__global__ __launch_bounds__(256) void k_gemm2(const float* __restrict__ a,
                                               const float* __restrict__ W,
                                               const float* __restrict__ dinv,
                                               float* __restrict__ hs2) {
    __shared__ float wl[F1 * F2];   // 10 KB
    const int tid = threadIdx.x;
    for (int i = tid; i < F1 * F2; i += 256) wl[i] = W[i];
    __syncthreads();

    int r = blockIdx.x * 256 + tid;
    if (r >= NN) return;

    float acc[F2];
    #pragma unroll
    for (int j = 0; j < F2; ++j) acc[j] = 0.0f;

    const float* arow = a + (size_t)r * F1;
    for (int k0 = 0; k0 < F1; k0 += 4) {
        float4 av = *(const float4*)&arow[k0];
        #pragma unroll
        for (int j0 = 0; j0 < F2; j0 += 4) {
            float4 w0 = *(float4*)&wl[(k0 + 0) * F2 + j0];
            float4 w1 = *(float4*)&wl[(k0 + 1) * F2 + j0];
            float4 w2 = *(float4*)&wl[(k0 + 2) * F2 + j0];
            float4 w3 = *(float4*)&wl[(k0 + 3) * F2 + j0];
            acc[j0 + 0] += av.x * w0.x + av.y * w1.x + av.z * w2.x + av.w * w3.x;
            acc[j0 + 1] += av.x * w0.y + av.y * w1.y + av.z * w2.y + av.w * w3.y;
            acc[j0 + 2] += av.x * w0.z + av.y * w1.z + av.z * w2.z + av.w * w3.z;
            acc[j0 + 3] += av.x * w0.w + av.y * w1.w + av.z * w2.w + av.w * w3.w;
        }
    }

    float dv = dinv[r];
    #pragma unroll
    for (int j0 = 0; j0 < F2; j0 += 4) {
        float4 v;
        v.x = acc[j0 + 0] * dv;
        v.y = acc[j0 + 1] * dv;
        v.z = acc[j0 + 2] * dv;
        v.w = acc[j0 + 3] * dv;
        *(float4*)&hs2[(size_t)r * F2 + j0] = v;
    }
}

// ---------------- gather2: out = dinv*(hs2[i] + sum_nbr hs2[s]) + b2 ----------------
// 10 lanes per node (F2 = 40 = 10 x float4), 320-thread blocks = 32 nodes/block
__global__ __launch_bounds__(320) void k_gather2(const int* __restrict__ rs,
                                                 const int* __restrict__ ce,
                                                 const int* __restrict__ csr,
                                                 const float* __restrict__ hs2,
                                                 const float* __restrict__ dinv,
                                                 const float* __restrict__ b,
                                                 float* __restrict__ outp) {
    int t = blockIdx.x * 320 + threadIdx.x;   // t < 1,000,000 exact
    int i = t / 10;
    int g = t - i * 10;
    float4 acc = *(const float4*)&hs2[(size_t)i * F2 + g * 4];   // self-loop
    int k = rs[i], end = ce[i];
    for (; k + 4 <= end; k += 4) {
        int s0 = csr[k], s1 = csr[k + 1], s2 = csr[k + 2], s3 = csr[k + 3];
        float4 v0 = *(const float4*)&hs2[(size_t)s0 * F2 + g * 4];
        float4 v1 = *(const float4*)&hs2[(size_t)s1 * F2 + g * 4];
        float4 v2 = *(const float4*)&hs2[(size_t)s2 * F2 + g * 4];
        float4 v3 = *(const float4*)&hs2[(size_t)s3 * F2 + g * 4];
        acc.x += (v0.x + v1.x) + (v2.x + v3.x);
        acc.y += (v0.y + v1.y) + (v2.y + v3.y);
        acc.z += (v0.z + v1.z) + (v2.z + v3.z);
        acc.w += (v0.w + v1.w) + (v2.w + v3.w);
    }
    for (; k < end; ++k) {
        int s0 = csr[k];
        float4 v0 = *(const float4*)&hs2[(size_t)s0 * F2 + g * 4];
        acc.x += v0.x; acc.y += v0.y; acc.z += v0.z; acc.w += v0.w;
    }
    float dv = dinv[i];
    float4 bb = *(const float4*)&b[g * 4];
    float4 r;
    r.x = fmaf(dv, acc.x, bb.x);
    r.y = fmaf(dv, acc.y, bb.y);
    r.z = fmaf(dv, acc.z, bb.z);
    r.w = fmaf(dv, acc.w, bb.w);
    *(float4*)&outp[(size_t)i * F2 + g * 4] = r;
}

extern "C" void kernel_launch(void* const* d_in, const int* in_sizes, int n_in,
                              void* d_out, int out_size, void* d_ws, size_t ws_size,
                              hipStream_t stream) {
    const float* x  = (const float*)d_in[0];
    const int*   ei = (const int*)d_in[1];
    const float* W1 = (const float*)d_in[2];
    const float* b1 = (const float*)d_in[3];
    const float* W2 = (const float*)d_in[4];
    const float* b2 = (const float*)d_in[5];
    float* out = (float*)d_out;

    const int* src = ei;
    const int* dst = ei + NE;

    // workspace layout in 4-byte units (total ~59 MB):
    // [dinv 102400][rs 102400][ce 102400][bucketCnt 256 + gCursor 1, pad->1024]
    // [csr 1.6M][bufA 6.4M][bufB 6.4M]
    // bucket (256*8192 = 2.1M u32) aliases bufB: fully consumed by k_build
    // before gather1 writes bufB.
    float* dinv      = (float*)d_ws;
    int*   rs        = (int*)d_ws + 102400;
    int*   ce        = (int*)d_ws + 204800;
    int*   bucketCnt = (int*)d_ws + 307200;       // [0..255]=counts, [256]=gCursor
    int*   csr       = (int*)d_ws + 308224;
    float* bufA      = (float*)d_ws + 308224 + NE;
    float* bufB      = bufA + (size_t)NN * F1;
    unsigned* bucket = (unsigned*)bufB;

    // CSR + dinv build: 2 passes, no per-edge global atomics
    k_zero<<<1, 512, 0, stream>>>(bucketCnt);
    k_part<<<512, 256, 0, stream>>>(src, dst, bucketCnt, bucket);
    k_build<<<NB, 512, 0, stream>>>(bucketCnt, bucket, bucketCnt + NB,
                                    rs, ce, csr, dinv);

    // layer 1
    k_gemm1<<<NN / 32, 256, 0, stream>>>(x, W1, dinv, bufA);
    k_gather1<<<NN * 16 / 256, 256, 0, stream>>>(rs, ce, csr, bufA, dinv, b1, bufB);

    // layer 2
    k_gemm2<<<(NN + 255) / 256, 256, 0, stream>>>(bufB, W2, dinv, bufA);
    k_gather2<<<NN / 32, 320, 0, stream>>>(rs, ce, csr, bufA, dinv, b2, out);
}

// Round 6
// 183.507 us; speedup vs baseline: 13.8447x; 1.2494x over previous
//
#include <hip/hip_runtime.h>
#include <hip/hip_fp16.h>
#include <math.h>

#define NN 100000
#define NE 1600000
#define F0 128
#define F1 64
#define F2 40
#define NB 256         // buckets = CSR-build blocks
#define BSZ 391        // nodes per bucket (391*256 = 100096 >= NN)
#define CAP2 8192      // bucket capacity (mean 6250, sigma 79 -> 24 sigma)
#define CHUNK 3125     // NE / 512 partition blocks

// ---------------- zero counters: bucketCnt[256] + gCursor ----------------
__global__ void k_zero(int* __restrict__ p) {
    if (threadIdx.x < NB + 1) p[threadIdx.x] = 0;
}

// ---------------- phase A: 256-bucket partition by dst sub-range ----------------
// pack = (loc << 17) | src,  loc = dst - b*BSZ (< 391 < 2^9), src < 2^17
__global__ __launch_bounds__(256) void k_part(const int* __restrict__ src,
                                              const int* __restrict__ dst,
                                              int* __restrict__ bucketCnt,
                                              unsigned* __restrict__ bucket) {
    __shared__ int cnt[NB], base[NB];
    const int tid = threadIdx.x;
    cnt[tid] = 0;
    __syncthreads();
    const int e0 = blockIdx.x * CHUNK;
    const int e1 = e0 + CHUNK;   // 512 * 3125 == NE exactly
    for (int e = e0 + tid; e < e1; e += 256)
        atomicAdd(&cnt[dst[e] / BSZ], 1);
    __syncthreads();
    base[tid] = atomicAdd(&bucketCnt[tid], cnt[tid]);
    cnt[tid] = 0;
    __syncthreads();
    for (int e = e0 + tid; e < e1; e += 256) {
        int d = dst[e];
        int b = d / BSZ;
        int loc = d - b * BSZ;
        int ofs = atomicAdd(&cnt[b], 1);
        bucket[(size_t)b * CAP2 + base[b] + ofs] = ((unsigned)loc << 17) | (unsigned)src[e];
    }
}

// ---------------- phase B: per-bucket CSR segment build ----------------
__global__ __launch_bounds__(512) void k_build(const int* __restrict__ bucketCnt,
                                               const unsigned* __restrict__ bucket,
                                               int* __restrict__ gCursor,
                                               int* __restrict__ rs,
                                               int* __restrict__ ce,
                                               int* __restrict__ csr,
                                               float* __restrict__ dinv) {
    __shared__ int cnt[512];
    __shared__ int sc[512];
    __shared__ int sh_base;

    const int tid = threadIdx.x;
    const int b = blockIdx.x;
    const int n0 = b * BSZ;
    const int nn = (NN - n0 < BSZ) ? (NN - n0) : BSZ;

    cnt[tid] = 0;
    __syncthreads();

    const int cntB = bucketCnt[b];
    const unsigned* bk = bucket + (size_t)b * CAP2;
    for (int idx = tid; idx < cntB; idx += 512)
        atomicAdd(&cnt[bk[idx] >> 17], 1);
    __syncthreads();

    // inclusive scan cnt -> sc
    sc[tid] = cnt[tid];
    __syncthreads();
    for (int off = 1; off < 512; off <<= 1) {
        int v = (tid >= off) ? sc[tid - off] : 0;
        __syncthreads();
        sc[tid] += v;
        __syncthreads();
    }

    const int T = sc[511];
    if (tid == 0) sh_base = atomicAdd(gCursor, T);
    __syncthreads();
    const int base = sh_base;

    if (tid < nn) {
        int c = cnt[tid];
        int excl = sc[tid] - c;
        rs[n0 + tid] = base + excl;
        ce[n0 + tid] = base + sc[tid];
        dinv[n0 + tid] = rsqrtf((float)(c + 1));   // +1 self-loop
        sc[tid] = excl;
    }
    cnt[tid] = 0;
    __syncthreads();

    for (int idx = tid; idx < cntB; idx += 512) {
        unsigned p = bk[idx];
        int l = (int)(p >> 17);
        int ofs = atomicAdd(&cnt[l], 1);
        csr[base + sc[l] + ofs] = (int)(p & 0x1FFFFu);
    }
}

// ---------------- fp16 accumulate helpers ----------------
__device__ __forceinline__ void acc8(float a[8], uint4 u) {
    __half2 h0 = *(__half2*)&u.x, h1 = *(__half2*)&u.y;
    __half2 h2 = *(__half2*)&u.z, h3 = *(__half2*)&u.w;
    float2 f0 = __half22float2(h0), f1 = __half22float2(h1);
    float2 f2 = __half22float2(h2), f3 = __half22float2(h3);
    a[0] += f0.x; a[1] += f0.y; a[2] += f1.x; a[3] += f1.y;
    a[4] += f2.x; a[5] += f2.y; a[6] += f3.x; a[7] += f3.y;
}

__device__ __forceinline__ void acc4(float a[4], uint2 u) {
    __half2 h0 = *(__half2*)&u.x, h1 = *(__half2*)&u.y;
    float2 f0 = __half22float2(h0), f1 = __half22float2(h1);
    a[0] += f0.x; a[1] += f0.y; a[2] += f1.x; a[3] += f1.y;
}

// ---------------- GEMM1: hs(fp16) = dinv[row] * (x @ W1) ----------------
__global__ __launch_bounds__(256) void k_gemm1(const float* __restrict__ x,
                                               const float* __restrict__ W,
                                               const float* __restrict__ dinv,
                                               __half* __restrict__ hs) {
    __shared__ float wl[F0 * F1];   // 32 KB
    __shared__ float xl[32 * F0];   // 16 KB
    const int tid = threadIdx.x;
    const int row0 = blockIdx.x * 32;

    #pragma unroll
    for (int i = tid * 4; i < F0 * F1; i += 256 * 4)
        *(float4*)&wl[i] = *(const float4*)&W[i];
    #pragma unroll
    for (int i = tid * 4; i < 32 * F0; i += 256 * 4)
        *(float4*)&xl[i] = *(const float4*)&x[(size_t)row0 * F0 + i];
    __syncthreads();

    const int j = tid & 63;
    const int rg = tid >> 6;    // 0..3
    float acc[8];
    #pragma unroll
    for (int rr = 0; rr < 8; ++rr) acc[rr] = 0.0f;

    for (int k0 = 0; k0 < F0; k0 += 4) {
        float w0 = wl[(k0 + 0) * F1 + j];
        float w1 = wl[(k0 + 1) * F1 + j];
        float w2 = wl[(k0 + 2) * F1 + j];
        float w3 = wl[(k0 + 3) * F1 + j];
        #pragma unroll
        for (int rr = 0; rr < 8; ++rr) {
            float4 xv = *(float4*)&xl[(rg * 8 + rr) * F0 + k0];
            acc[rr] += xv.x * w0 + xv.y * w1 + xv.z * w2 + xv.w * w3;
        }
    }

    #pragma unroll
    for (int rr = 0; rr < 8; ++rr) {
        int r = row0 + rg * 8 + rr;   // 3125*32 == 100000 exactly
        hs[(size_t)r * F1 + j] = __float2half(acc[rr] * dinv[r]);
    }
}

// ---------------- gather1: a1(fp32) = relu(dinv*(hs[i] + sum_nbr hs[s]) + b1) ----
// 8 lanes per node, 8 halfs (16 B) per lane; grid = NN*8/256 = 3125 exact
__global__ __launch_bounds__(256) void k_gather1(const int* __restrict__ rs,
                                                 const int* __restrict__ ce,
                                                 const int* __restrict__ csr,
                                                 const __half* __restrict__ hs,
                                                 const float* __restrict__ dinv,
                                                 const float* __restrict__ b,
                                                 float* __restrict__ outp) {
    int t = blockIdx.x * 256 + threadIdx.x;
    int i = t >> 3;
    int g = t & 7;
    float acc[8] = {0, 0, 0, 0, 0, 0, 0, 0};
    acc8(acc, *(const uint4*)&hs[(size_t)i * F1 + g * 8]);   // self-loop
    int k = rs[i], end = ce[i];
    for (; k + 4 <= end; k += 4) {
        int s0 = csr[k], s1 = csr[k + 1], s2 = csr[k + 2], s3 = csr[k + 3];
        uint4 u0 = *(const uint4*)&hs[(size_t)s0 * F1 + g * 8];
        uint4 u1 = *(const uint4*)&hs[(size_t)s1 * F1 + g * 8];
        uint4 u2 = *(const uint4*)&hs[(size_t)s2 * F1 + g * 8];
        uint4 u3 = *(const uint4*)&hs[(size_t)s3 * F1 + g * 8];
        acc8(acc, u0); acc8(acc, u1); acc8(acc, u2); acc8(acc, u3);
    }
    for (; k < end; ++k)
        acc8(acc, *(const uint4*)&hs[(size_t)csr[k] * F1 + g * 8]);

    float dv = dinv[i];
    float4 b0 = *(const float4*)&b[g * 8];
    float4 b1v = *(const float4*)&b[g * 8 + 4];
    float4 r0, r1;
    r0.x = fmaxf(fmaf(dv, acc[0], b0.x), 0.0f);
    r0.y = fmaxf(fmaf(dv, acc[1], b0.y), 0.0f);
    r0.z = fmaxf(fmaf(dv, acc[2], b0.z), 0.0f);
    r0.w = fmaxf(fmaf(dv, acc[3], b0.w), 0.0f);
    r1.x = fmaxf(fmaf(dv, acc[4], b1v.x), 0.0f);
    r1.y = fmaxf(fmaf(dv, acc[5], b1v.y), 0.0f);
    r1.z = fmaxf(fmaf(dv, acc[6], b1v.z), 0.0f);
    r1.w = fmaxf(fmaf(dv, acc[7], b1v.w), 0.0f);
    *(float4*)&outp[(size_t)i * F1 + g * 8]     = r0;
    *(float4*)&outp[(size_t)i * F1 + g * 8 + 4] = r1;
}

// ---------------- GEMM2: hs2(fp16) = dinv[row] * (a1 @ W2) ----------------
__global__ __launch_bounds__(256) void k_gemm2(const float* __restrict__ a,
                                               const float* __restrict__ W,
                                               const float* __restrict__ dinv,
                                               __half* __restrict__ hs2) {
    __shared__ float wl[F1 * F2];   // 10 KB
    const int tid = threadIdx.x;
    for (int i = tid; i < F1 * F2; i += 256) wl[i] = W[i];
    __syncthreads();

    int r = blockIdx.x * 256 + tid;
    if (r >= NN) return;

    float acc[F2];
    #pragma unroll
    for (int j = 0; j < F2; ++j) acc[j] = 0.0f;

    const float* arow = a + (size_t)r * F1;
    for (int k0 = 0; k0 < F1; k0 += 4) {
        float4 av = *(const float4*)&arow[k0];
        #pragma unroll
        for (int j0 = 0; j0 < F2; j0 += 4) {
            float4 w0 = *(float4*)&wl[(k0 + 0) * F2 + j0];
            float4 w1 = *(float4*)&wl[(k0 + 1) * F2 + j0];
            float4 w2 = *(float4*)&wl[(k0 + 2) * F2 + j0];
            float4 w3 = *(float4*)&wl[(k0 + 3) * F2 + j0];
            acc[j0 + 0] += av.x * w0.x + av.y * w1.x + av.z * w2.x + av.w * w3.x;
            acc[j0 + 1] += av.x * w0.y + av.y * w1.y + av.z * w2.y + av.w * w3.y;
            acc[j0 + 2] += av.x * w0.z + av.y * w1.z + av.z * w2.z + av.w * w3.z;
            acc[j0 + 3] += av.x * w0.w + av.y * w1.w + av.z * w2.w + av.w * w3.w;
        }
    }

    float dv = dinv[r];
    __half2* o = (__half2*)&hs2[(size_t)r * F2];
    #pragma unroll
    for (int j0 = 0; j0 < F2; j0 += 2)
        o[j0 >> 1] = __floats2half2_rn(acc[j0] * dv, acc[j0 + 1] * dv);
}

// ---------------- gather2: out = dinv*(hs2[i] + sum_nbr hs2[s]) + b2 ----------------
// 10 lanes per node, 4 halfs (8 B) per lane; 320-thread blocks, grid 3125 exact
__global__ __launch_bounds__(320) void k_gather2(const int* __restrict__ rs,
                                                 const int* __restrict__ ce,
                                                 const int* __restrict__ csr,
                                                 const __half* __restrict__ hs2,
                                                 const float* __restrict__ dinv,
                                                 const float* __restrict__ b,
                                                 float* __restrict__ outp) {
    int t = blockIdx.x * 320 + threadIdx.x;   // t < 1,000,000 exact
    int i = t / 10;
    int g = t - i * 10;
    float acc[4] = {0, 0, 0, 0};
    acc4(acc, *(const uint2*)&hs2[(size_t)i * F2 + g * 4]);   // self-loop
    int k = rs[i], end = ce[i];
    for (; k + 4 <= end; k += 4) {
        int s0 = csr[k], s1 = csr[k + 1], s2 = csr[k + 2], s3 = csr[k + 3];
        uint2 u0 = *(const uint2*)&hs2[(size_t)s0 * F2 + g * 4];
        uint2 u1 = *(const uint2*)&hs2[(size_t)s1 * F2 + g * 4];
        uint2 u2 = *(const uint2*)&hs2[(size_t)s2 * F2 + g * 4];
        uint2 u3 = *(const uint2*)&hs2[(size_t)s3 * F2 + g * 4];
        acc4(acc, u0); acc4(acc, u1); acc4(acc, u2); acc4(acc, u3);
    }
    for (; k < end; ++k)
        acc4(acc, *(const uint2*)&hs2[(size_t)csr[k] * F2 + g * 4]);

    float dv = dinv[i];
    float4 bb = *(const float4*)&b[g * 4];
    float4 r;
    r.x = fmaf(dv, acc[0], bb.x);
    r.y = fmaf(dv, acc[1], bb.y);
    r.z = fmaf(dv, acc[2], bb.z);
    r.w = fmaf(dv, acc[3], bb.w);
    *(float4*)&outp[(size_t)i * F2 + g * 4] = r;
}

extern "C" void kernel_launch(void* const* d_in, const int* in_sizes, int n_in,
                              void* d_out, int out_size, void* d_ws, size_t ws_size,
                              hipStream_t stream) {
    const float* x  = (const float*)d_in[0];
    const int*   ei = (const int*)d_in[1];
    const float* W1 = (const float*)d_in[2];
    const float* b1 = (const float*)d_in[3];
    const float* W2 = (const float*)d_in[4];
    const float* b2 = (const float*)d_in[5];
    float* out = (float*)d_out;

    const int* src = ei;
    const int* dst = ei + NE;

    // workspace layout in 4-byte units (total ~59 MB):
    // [dinv 102400][rs 102400][ce 102400][bucketCnt 256 + gCursor, pad->1024]
    // [csr 1.6M][bufA 6.4M][bufB 6.4M]
    // bucket (256*8192 u32) aliases bufB: fully consumed by k_build before
    // gather1 writes bufB. hs (fp16) lives in bufA.
    float* dinv      = (float*)d_ws;
    int*   rs        = (int*)d_ws + 102400;
    int*   ce        = (int*)d_ws + 204800;
    int*   bucketCnt = (int*)d_ws + 307200;       // [0..255]=counts, [256]=gCursor
    int*   csr       = (int*)d_ws + 308224;
    float* bufA      = (float*)d_ws + 308224 + NE;
    float* bufB      = bufA + (size_t)NN * F1;
    unsigned* bucket = (unsigned*)bufB;
    __half* hs1      = (__half*)bufA;             // N x 64 fp16 (12.8 MB)
    __half* hs2      = (__half*)bufA;             // N x 40 fp16 (8 MB), after gather1

    // CSR + dinv build: 2 passes, no per-edge global atomics
    k_zero<<<1, 512, 0, stream>>>(bucketCnt);
    k_part<<<512, 256, 0, stream>>>(src, dst, bucketCnt, bucket);
    k_build<<<NB, 512, 0, stream>>>(bucketCnt, bucket, bucketCnt + NB,
                                    rs, ce, csr, dinv);

    // layer 1
    k_gemm1<<<NN / 32, 256, 0, stream>>>(x, W1, dinv, hs1);
    k_gather1<<<NN * 8 / 256, 256, 0, stream>>>(rs, ce, csr, hs1, dinv, b1, bufB);

    // layer 2
    k_gemm2<<<(NN + 255) / 256, 256, 0, stream>>>(bufB, W2, dinv, hs2);
    k_gather2<<<NN / 32, 320, 0, stream>>>(rs, ce, csr, hs2, dinv, b2, out);
}

// Round 7
// 140.604 us; speedup vs baseline: 18.0691x; 1.3051x over previous
//
#include <hip/hip_runtime.h>
#include <hip/hip_fp16.h>
#include <math.h>

#define NN 100000
#define NE 1600000
#define F0 128
#define F1 64
#define F2 40
#define NB 256         // buckets = CSR-build blocks
#define BSZ 391        // nodes per bucket (391*256 = 100096 >= NN)
#define CAP2 8192      // bucket capacity (mean 6250, sigma 79 -> 24 sigma)
#define CHUNK 3125     // NE / 512 partition blocks

typedef _Float16 f16x8 __attribute__((ext_vector_type(8)));
typedef _Float16 f16x4 __attribute__((ext_vector_type(4)));
typedef float f32x4 __attribute__((ext_vector_type(4)));

// ---------------- zero counters: bucketCnt[256] + gCursor ----------------
__global__ void k_zero(int* __restrict__ p) {
    if (threadIdx.x < NB + 1) p[threadIdx.x] = 0;
}

// ---------------- prep: W1^T and W2^T (zero-padded to 48 cols) in fp16 ----------------
__global__ __launch_bounds__(256) void k_prepW(const float* __restrict__ W1,
                                               const float* __restrict__ W2,
                                               _Float16* __restrict__ w1t,
                                               _Float16* __restrict__ w2t) {
    int idx = blockIdx.x * 256 + threadIdx.x;
    if (idx < 64 * 128) {                  // w1t[n][k], n<64, k<128
        int n = idx >> 7, k = idx & 127;
        w1t[idx] = (_Float16)W1[k * 64 + n];
    } else if (idx < 64 * 128 + 48 * 64) { // w2t[n][k], n<48, k<64
        int j = idx - 64 * 128;
        int n = j >> 6, k = j & 63;
        w2t[j] = (_Float16)(n < 40 ? W2[k * 40 + n] : 0.0f);
    }
}

// ---------------- phase A: 256-bucket partition by dst sub-range ----------------
__global__ __launch_bounds__(256) void k_part(const int* __restrict__ src,
                                              const int* __restrict__ dst,
                                              int* __restrict__ bucketCnt,
                                              unsigned* __restrict__ bucket) {
    __shared__ int cnt[NB], base[NB];
    const int tid = threadIdx.x;
    cnt[tid] = 0;
    __syncthreads();
    const int e0 = blockIdx.x * CHUNK;
    const int e1 = e0 + CHUNK;   // 512 * 3125 == NE exactly
    for (int e = e0 + tid; e < e1; e += 256)
        atomicAdd(&cnt[dst[e] / BSZ], 1);
    __syncthreads();
    base[tid] = atomicAdd(&bucketCnt[tid], cnt[tid]);
    cnt[tid] = 0;
    __syncthreads();
    for (int e = e0 + tid; e < e1; e += 256) {
        int d = dst[e];
        int b = d / BSZ;
        int loc = d - b * BSZ;
        int ofs = atomicAdd(&cnt[b], 1);
        bucket[(size_t)b * CAP2 + base[b] + ofs] = ((unsigned)loc << 17) | (unsigned)src[e];
    }
}

// ---------------- phase B: per-bucket CSR segment build ----------------
__global__ __launch_bounds__(512) void k_build(const int* __restrict__ bucketCnt,
                                               const unsigned* __restrict__ bucket,
                                               int* __restrict__ gCursor,
                                               int* __restrict__ rs,
                                               int* __restrict__ ce,
                                               int* __restrict__ csr,
                                               float* __restrict__ dinv) {
    __shared__ int cnt[512];
    __shared__ int sc[512];
    __shared__ int sh_base;

    const int tid = threadIdx.x;
    const int b = blockIdx.x;
    const int n0 = b * BSZ;
    const int nn = (NN - n0 < BSZ) ? (NN - n0) : BSZ;

    cnt[tid] = 0;
    __syncthreads();

    const int cntB = bucketCnt[b];
    const unsigned* bk = bucket + (size_t)b * CAP2;
    for (int idx = tid; idx < cntB; idx += 512)
        atomicAdd(&cnt[bk[idx] >> 17], 1);
    __syncthreads();

    sc[tid] = cnt[tid];
    __syncthreads();
    for (int off = 1; off < 512; off <<= 1) {
        int v = (tid >= off) ? sc[tid - off] : 0;
        __syncthreads();
        sc[tid] += v;
        __syncthreads();
    }

    const int T = sc[511];
    if (tid == 0) sh_base = atomicAdd(gCursor, T);
    __syncthreads();
    const int base = sh_base;

    if (tid < nn) {
        int c = cnt[tid];
        int excl = sc[tid] - c;
        rs[n0 + tid] = base + excl;
        ce[n0 + tid] = base + sc[tid];
        dinv[n0 + tid] = rsqrtf((float)(c + 1));   // +1 self-loop
        sc[tid] = excl;
    }
    cnt[tid] = 0;
    __syncthreads();

    for (int idx = tid; idx < cntB; idx += 512) {
        unsigned p = bk[idx];
        int l = (int)(p >> 17);
        int ofs = atomicAdd(&cnt[l], 1);
        csr[base + sc[l] + ofs] = (int)(p & 0x1FFFFu);
    }
}

// ---------------- fp16 accumulate helpers ----------------
__device__ __forceinline__ void acc8(float a[8], uint4 u) {
    __half2 h0 = *(__half2*)&u.x, h1 = *(__half2*)&u.y;
    __half2 h2 = *(__half2*)&u.z, h3 = *(__half2*)&u.w;
    float2 f0 = __half22float2(h0), f1 = __half22float2(h1);
    float2 f2 = __half22float2(h2), f3 = __half22float2(h3);
    a[0] += f0.x; a[1] += f0.y; a[2] += f1.x; a[3] += f1.y;
    a[4] += f2.x; a[5] += f2.y; a[6] += f3.x; a[7] += f3.y;
}

__device__ __forceinline__ void acc4(float a[4], uint2 u) {
    __half2 h0 = *(__half2*)&u.x, h1 = *(__half2*)&u.y;
    float2 f0 = __half22float2(h0), f1 = __half22float2(h1);
    a[0] += f0.x; a[1] += f0.y; a[2] += f1.x; a[3] += f1.y;
}

// ---------------- GEMM1 (MFMA): hs(fp16) = dinv[row] * (x @ W1) ----------------
// 64 rows/block, 4 waves; wave w computes rows [w*16,+16) x 64 cols.
// A/B fragments use the same (lane>>4, elem)->k bijection -> correct contraction.
__global__ __launch_bounds__(256) void k_gemm1(const float* __restrict__ x,
                                               const _Float16* __restrict__ w1t,
                                               const float* __restrict__ dinv,
                                               _Float16* __restrict__ hs) {
    __shared__ _Float16 xl[64][136];   // +8 pad: 272B rows, 16B-aligned
    __shared__ _Float16 wl[64][136];   // wl[n][k]
    const int tid = threadIdx.x;
    const int row0 = blockIdx.x * 64;

    // stage W1^T (fp16, contiguous 1024 uint4)
    for (int i = tid; i < 1024; i += 256) {
        uint4 v = ((const uint4*)w1t)[i];
        int n = i >> 4, c = i & 15;
        *(uint4*)&wl[n][c * 8] = v;
    }
    // stage x tile: 4 threads/row, 32 floats each, fp32->fp16
    {
        int r = tid >> 2, part = tid & 3;
        int gr = row0 + r; if (gr >= NN) gr = NN - 1;
        const float* xr = x + (size_t)gr * F0 + part * 32;
        _Float16* dstp = &xl[r][part * 32];
        #pragma unroll
        for (int q = 0; q < 8; ++q) {
            float4 v = *(const float4*)&xr[q * 4];
            f16x4 h;
            h[0] = (_Float16)v.x; h[1] = (_Float16)v.y;
            h[2] = (_Float16)v.z; h[3] = (_Float16)v.w;
            *(f16x4*)&dstp[q * 4] = h;
        }
    }
    __syncthreads();

    const int wave = tid >> 6;
    const int lane = tid & 63;
    const int l16 = lane & 15;
    const int g8 = (lane >> 4) * 8;

    f32x4 acc[4] = {{0,0,0,0},{0,0,0,0},{0,0,0,0},{0,0,0,0}};
    #pragma unroll
    for (int k0 = 0; k0 < F0; k0 += 32) {
        f16x8 a = *(f16x8*)&xl[wave * 16 + l16][k0 + g8];
        #pragma unroll
        for (int ct = 0; ct < 4; ++ct) {
            f16x8 b = *(f16x8*)&wl[ct * 16 + l16][k0 + g8];
            acc[ct] = __builtin_amdgcn_mfma_f32_16x16x32_f16(a, b, acc[ct], 0, 0, 0);
        }
    }

    const int baserow = row0 + wave * 16 + (lane >> 4) * 4;
    #pragma unroll
    for (int j = 0; j < 4; ++j) {
        int gr = baserow + j;
        if (gr < NN) {
            float dv = dinv[gr];
            #pragma unroll
            for (int ct = 0; ct < 4; ++ct)
                hs[(size_t)gr * F1 + ct * 16 + l16] = (_Float16)(acc[ct][j] * dv);
        }
    }
}

// ---------------- gather1: a1(fp16) = relu(dinv*(hs[i] + sum_nbr hs[s]) + b1) ----
// 8 lanes per node, 8 halfs (16 B) per lane; grid = NN*8/256 = 3125 exact
__global__ __launch_bounds__(256) void k_gather1(const int* __restrict__ rs,
                                                 const int* __restrict__ ce,
                                                 const int* __restrict__ csr,
                                                 const __half* __restrict__ hs,
                                                 const float* __restrict__ dinv,
                                                 const float* __restrict__ b,
                                                 _Float16* __restrict__ outp) {
    int t = blockIdx.x * 256 + threadIdx.x;
    int i = t >> 3;
    int g = t & 7;
    float acc[8] = {0, 0, 0, 0, 0, 0, 0, 0};
    acc8(acc, *(const uint4*)&hs[(size_t)i * F1 + g * 8]);   // self-loop
    int k = rs[i], end = ce[i];
    for (; k + 4 <= end; k += 4) {
        int s0 = csr[k], s1 = csr[k + 1], s2 = csr[k + 2], s3 = csr[k + 3];
        uint4 u0 = *(const uint4*)&hs[(size_t)s0 * F1 + g * 8];
        uint4 u1 = *(const uint4*)&hs[(size_t)s1 * F1 + g * 8];
        uint4 u2 = *(const uint4*)&hs[(size_t)s2 * F1 + g * 8];
        uint4 u3 = *(const uint4*)&hs[(size_t)s3 * F1 + g * 8];
        acc8(acc, u0); acc8(acc, u1); acc8(acc, u2); acc8(acc, u3);
    }
    for (; k < end; ++k)
        acc8(acc, *(const uint4*)&hs[(size_t)csr[k] * F1 + g * 8]);

    float dv = dinv[i];
    float4 b0 = *(const float4*)&b[g * 8];
    float4 b1v = *(const float4*)&b[g * 8 + 4];
    f16x8 o;
    o[0] = (_Float16)fmaxf(fmaf(dv, acc[0], b0.x), 0.0f);
    o[1] = (_Float16)fmaxf(fmaf(dv, acc[1], b0.y), 0.0f);
    o[2] = (_Float16)fmaxf(fmaf(dv, acc[2], b0.z), 0.0f);
    o[3] = (_Float16)fmaxf(fmaf(dv, acc[3], b0.w), 0.0f);
    o[4] = (_Float16)fmaxf(fmaf(dv, acc[4], b1v.x), 0.0f);
    o[5] = (_Float16)fmaxf(fmaf(dv, acc[5], b1v.y), 0.0f);
    o[6] = (_Float16)fmaxf(fmaf(dv, acc[6], b1v.z), 0.0f);
    o[7] = (_Float16)fmaxf(fmaf(dv, acc[7], b1v.w), 0.0f);
    *(f16x8*)&outp[(size_t)i * F1 + g * 8] = o;
}

// ---------------- GEMM2 (MFMA): hs2(fp16) = dinv[row] * (a1 @ W2) ----------------
// 64 rows/block, 4 waves, 48 padded cols (3 col-tiles), K=64 (2 k-steps)
__global__ __launch_bounds__(256) void k_gemm2(const _Float16* __restrict__ a1,
                                               const _Float16* __restrict__ w2t,
                                               const float* __restrict__ dinv,
                                               _Float16* __restrict__ hs2) {
    __shared__ _Float16 al[64][72];    // +8 pad: 144B rows
    __shared__ _Float16 wl2[48][72];
    const int tid = threadIdx.x;
    const int row0 = blockIdx.x * 64;

    for (int i = tid; i < 512; i += 256) {          // a1 tile: 64 rows x 8 uint4
        int r = i >> 3, c = i & 7;
        int gr = row0 + r; if (gr >= NN) gr = NN - 1;
        *(uint4*)&al[r][c * 8] = ((const uint4*)a1)[(size_t)gr * 8 + c];
    }
    for (int i = tid; i < 384; i += 256) {          // w2t: 48 rows x 8 uint4
        int n = i >> 3, c = i & 7;
        *(uint4*)&wl2[n][c * 8] = ((const uint4*)w2t)[i];
    }
    __syncthreads();

    const int wave = tid >> 6;
    const int lane = tid & 63;
    const int l16 = lane & 15;
    const int g8 = (lane >> 4) * 8;

    f32x4 acc[3] = {{0,0,0,0},{0,0,0,0},{0,0,0,0}};
    #pragma unroll
    for (int k0 = 0; k0 < F1; k0 += 32) {
        f16x8 a = *(f16x8*)&al[wave * 16 + l16][k0 + g8];
        #pragma unroll
        for (int ct = 0; ct < 3; ++ct) {
            f16x8 b = *(f16x8*)&wl2[ct * 16 + l16][k0 + g8];
            acc[ct] = __builtin_amdgcn_mfma_f32_16x16x32_f16(a, b, acc[ct], 0, 0, 0);
        }
    }

    const int baserow = row0 + wave * 16 + (lane >> 4) * 4;
    #pragma unroll
    for (int j = 0; j < 4; ++j) {
        int gr = baserow + j;
        if (gr < NN) {
            float dv = dinv[gr];
            #pragma unroll
            for (int ct = 0; ct < 3; ++ct) {
                int col = ct * 16 + l16;
                if (col < F2)
                    hs2[(size_t)gr * F2 + col] = (_Float16)(acc[ct][j] * dv);
            }
        }
    }
}

// ---------------- gather2: out = dinv*(hs2[i] + sum_nbr hs2[s]) + b2 ----------------
// 10 lanes per node, 4 halfs (8 B) per lane; 320-thread blocks, grid 3125 exact
__global__ __launch_bounds__(320) void k_gather2(const int* __restrict__ rs,
                                                 const int* __restrict__ ce,
                                                 const int* __restrict__ csr,
                                                 const __half* __restrict__ hs2,
                                                 const float* __restrict__ dinv,
                                                 const float* __restrict__ b,
                                                 float* __restrict__ outp) {
    int t = blockIdx.x * 320 + threadIdx.x;   // t < 1,000,000 exact
    int i = t / 10;
    int g = t - i * 10;
    float acc[4] = {0, 0, 0, 0};
    acc4(acc, *(const uint2*)&hs2[(size_t)i * F2 + g * 4]);   // self-loop
    int k = rs[i], end = ce[i];
    for (; k + 4 <= end; k += 4) {
        int s0 = csr[k], s1 = csr[k + 1], s2 = csr[k + 2], s3 = csr[k + 3];
        uint2 u0 = *(const uint2*)&hs2[(size_t)s0 * F2 + g * 4];
        uint2 u1 = *(const uint2*)&hs2[(size_t)s1 * F2 + g * 4];
        uint2 u2 = *(const uint2*)&hs2[(size_t)s2 * F2 + g * 4];
        uint2 u3 = *(const uint2*)&hs2[(size_t)s3 * F2 + g * 4];
        acc4(acc, u0); acc4(acc, u1); acc4(acc, u2); acc4(acc, u3);
    }
    for (; k < end; ++k)
        acc4(acc, *(const uint2*)&hs2[(size_t)csr[k] * F2 + g * 4]);

    float dv = dinv[i];
    float4 bb = *(const float4*)&b[g * 4];
    float4 r;
    r.x = fmaf(dv, acc[0], bb.x);
    r.y = fmaf(dv, acc[1], bb.y);
    r.z = fmaf(dv, acc[2], bb.z);
    r.w = fmaf(dv, acc[3], bb.w);
    *(float4*)&outp[(size_t)i * F2 + g * 4] = r;
}

extern "C" void kernel_launch(void* const* d_in, const int* in_sizes, int n_in,
                              void* d_out, int out_size, void* d_ws, size_t ws_size,
                              hipStream_t stream) {
    const float* x  = (const float*)d_in[0];
    const int*   ei = (const int*)d_in[1];
    const float* W1 = (const float*)d_in[2];
    const float* b1 = (const float*)d_in[3];
    const float* W2 = (const float*)d_in[4];
    const float* b2 = (const float*)d_in[5];
    float* out = (float*)d_out;

    const int* src = ei;
    const int* dst = ei + NE;

    // workspace layout in 4-byte units (~33.3 MB):
    // [dinv 102400][rs 102400][ce 102400][bucketCnt 1024][w1t 4096][w2t 1536]
    // [csr 1.6M][bufA 3.2M (hs1/hs2 fp16)][bufB 3.2M (a1 fp16; bucket alias)]
    float*    dinv      = (float*)d_ws;
    int*      rs        = (int*)d_ws + 102400;
    int*      ce        = (int*)d_ws + 204800;
    int*      bucketCnt = (int*)d_ws + 307200;     // [0..255]=counts, [256]=gCursor
    _Float16* w1t       = (_Float16*)((int*)d_ws + 308224);  // 8192 halfs
    _Float16* w2t       = (_Float16*)((int*)d_ws + 312320);  // 3072 halfs
    int*      csr       = (int*)d_ws + 313856;
    _Float16* hsA       = (_Float16*)((int*)d_ws + 313856 + NE);      // NN*64 fp16
    _Float16* a1h       = (_Float16*)((int*)d_ws + 313856 + NE + 3200000); // NN*64 fp16
    unsigned* bucket    = (unsigned*)a1h;          // consumed by k_build first

    // CSR + dinv build + weight prep
    k_zero<<<1, 512, 0, stream>>>(bucketCnt);
    k_prepW<<<44, 256, 0, stream>>>(W1, W2, w1t, w2t);
    k_part<<<512, 256, 0, stream>>>(src, dst, bucketCnt, bucket);
    k_build<<<NB, 512, 0, stream>>>(bucketCnt, bucket, bucketCnt + NB,
                                    rs, ce, csr, dinv);

    // layer 1
    k_gemm1<<<(NN + 63) / 64, 256, 0, stream>>>(x, w1t, dinv, hsA);
    k_gather1<<<NN * 8 / 256, 256, 0, stream>>>(rs, ce, csr, (const __half*)hsA,
                                                dinv, b1, a1h);

    // layer 2
    k_gemm2<<<(NN + 63) / 64, 256, 0, stream>>>(a1h, w2t, dinv, hsA);
    k_gather2<<<NN / 32, 320, 0, stream>>>(rs, ce, csr, (const __half*)hsA,
                                           dinv, b2, out);
}

// Round 8
// 131.259 us; speedup vs baseline: 19.3556x; 1.0712x over previous
//
#include <hip/hip_runtime.h>
#include <hip/hip_fp16.h>
#include <math.h>

#define NN 100000
#define NE 1600000
#define F0 128
#define F1 64
#define F2 40
#define NB 256         // buckets = CSR-build blocks
#define BSZ 391        // nodes per bucket (391*256 = 100096 >= NN)
#define CAP2 8192      // bucket capacity (mean 6250, sigma 79 -> 24 sigma)
#define CHUNK 3125     // NE / 512 partition blocks
#define GEMM1_BLOCKS 1563   // ceil(NN/64)
#define PART_BLOCKS 512

typedef _Float16 f16x8 __attribute__((ext_vector_type(8)));
typedef _Float16 f16x4 __attribute__((ext_vector_type(4)));
typedef float f32x4 __attribute__((ext_vector_type(4)));

// ---------------- init: zero counters + W1^T / W2^T fp16 prep ----------------
__global__ __launch_bounds__(256) void k_init(const float* __restrict__ W1,
                                              const float* __restrict__ W2,
                                              _Float16* __restrict__ w1t,
                                              _Float16* __restrict__ w2t,
                                              int* __restrict__ bucketCnt) {
    int idx = blockIdx.x * 256 + threadIdx.x;
    if (idx <= NB) bucketCnt[idx] = 0;     // counts[256] + gCursor
    if (idx < 64 * 128) {                  // w1t[n][k], n<64, k<128
        int n = idx >> 7, k = idx & 127;
        w1t[idx] = (_Float16)W1[k * 64 + n];
    } else if (idx < 64 * 128 + 48 * 64) { // w2t[n][k], n<48 (pad), k<64
        int j = idx - 64 * 128;
        int n = j >> 6, k = j & 63;
        w2t[j] = (_Float16)(n < 40 ? W2[k * 40 + n] : 0.0f);
    }
}

// ---------------- fused: gemm1 (raw h, fp16) || 256-bucket edge partition --------
// blocks [0,1563): hs = x @ W1 (NO dinv scale -> independent of CSR build)
// blocks [1563,2075): partition edges into 256 dst-sub-range buckets
__global__ __launch_bounds__(256) void k_g1p(const float* __restrict__ x,
                                             const _Float16* __restrict__ w1t,
                                             const int* __restrict__ src,
                                             const int* __restrict__ dst,
                                             int* __restrict__ bucketCnt,
                                             unsigned* __restrict__ bucket,
                                             _Float16* __restrict__ hs) {
    __shared__ _Float16 xl[64][136];   // 17.4 KB (+8 pad: 2-way bank max)
    __shared__ _Float16 wl[64][136];   // 17.4 KB
    __shared__ int cnt[NB], base[NB];  // 2 KB (part path)
    const int tid = threadIdx.x;

    if (blockIdx.x < GEMM1_BLOCKS) {
        // ---- GEMM1 path ----
        const int row0 = blockIdx.x * 64;
        for (int i = tid; i < 1024; i += 256) {      // stage W1^T: 1024 uint4
            uint4 v = ((const uint4*)w1t)[i];
            *(uint4*)&wl[i >> 4][(i & 15) * 8] = v;
        }
        {   // stage x tile: 4 threads/row, 32 floats each, fp32->fp16
            int r = tid >> 2, part = tid & 3;
            int gr = row0 + r; if (gr >= NN) gr = NN - 1;
            const float* xr = x + (size_t)gr * F0 + part * 32;
            _Float16* dstp = &xl[r][part * 32];
            #pragma unroll
            for (int q = 0; q < 8; ++q) {
                float4 v = *(const float4*)&xr[q * 4];
                f16x4 h;
                h[0] = (_Float16)v.x; h[1] = (_Float16)v.y;
                h[2] = (_Float16)v.z; h[3] = (_Float16)v.w;
                *(f16x4*)&dstp[q * 4] = h;
            }
        }
        __syncthreads();

        const int wave = tid >> 6;
        const int lane = tid & 63;
        const int l16 = lane & 15;
        const int g8 = (lane >> 4) * 8;

        f32x4 acc[4] = {{0,0,0,0},{0,0,0,0},{0,0,0,0},{0,0,0,0}};
        #pragma unroll
        for (int k0 = 0; k0 < F0; k0 += 32) {
            f16x8 a = *(f16x8*)&xl[wave * 16 + l16][k0 + g8];
            #pragma unroll
            for (int ct = 0; ct < 4; ++ct) {
                f16x8 b = *(f16x8*)&wl[ct * 16 + l16][k0 + g8];
                acc[ct] = __builtin_amdgcn_mfma_f32_16x16x32_f16(a, b, acc[ct], 0, 0, 0);
            }
        }
        const int baserow = row0 + wave * 16 + (lane >> 4) * 4;
        #pragma unroll
        for (int j = 0; j < 4; ++j) {
            int gr = baserow + j;
            if (gr < NN) {
                #pragma unroll
                for (int ct = 0; ct < 4; ++ct)
                    hs[(size_t)gr * F1 + ct * 16 + l16] = (_Float16)acc[ct][j];
            }
        }
    } else {
        // ---- partition path ----
        const int pb = blockIdx.x - GEMM1_BLOCKS;
        cnt[tid] = 0;
        __syncthreads();
        const int e0 = pb * CHUNK;
        const int e1 = e0 + CHUNK;   // 512 * 3125 == NE exactly
        for (int e = e0 + tid; e < e1; e += 256)
            atomicAdd(&cnt[dst[e] / BSZ], 1);
        __syncthreads();
        base[tid] = atomicAdd(&bucketCnt[tid], cnt[tid]);
        cnt[tid] = 0;
        __syncthreads();
        for (int e = e0 + tid; e < e1; e += 256) {
            int d = dst[e];
            int b = d / BSZ;
            int loc = d - b * BSZ;
            int ofs = atomicAdd(&cnt[b], 1);
            bucket[(size_t)b * CAP2 + base[b] + ofs] =
                ((unsigned)loc << 17) | (unsigned)src[e];
        }
    }
}

// ---------------- phase B: per-bucket CSR segment build ----------------
__global__ __launch_bounds__(512) void k_build(const int* __restrict__ bucketCnt,
                                               const unsigned* __restrict__ bucket,
                                               int* __restrict__ gCursor,
                                               int* __restrict__ rs,
                                               int* __restrict__ ce,
                                               int* __restrict__ csr,
                                               float* __restrict__ dinv) {
    __shared__ int cnt[512];
    __shared__ int sc[512];
    __shared__ int sh_base;

    const int tid = threadIdx.x;
    const int b = blockIdx.x;
    const int n0 = b * BSZ;
    const int nn = (NN - n0 < BSZ) ? (NN - n0) : BSZ;

    cnt[tid] = 0;
    __syncthreads();

    const int cntB = bucketCnt[b];
    const unsigned* bk = bucket + (size_t)b * CAP2;
    for (int idx = tid; idx < cntB; idx += 512)
        atomicAdd(&cnt[bk[idx] >> 17], 1);
    __syncthreads();

    sc[tid] = cnt[tid];
    __syncthreads();
    for (int off = 1; off < 512; off <<= 1) {
        int v = (tid >= off) ? sc[tid - off] : 0;
        __syncthreads();
        sc[tid] += v;
        __syncthreads();
    }

    const int T = sc[511];
    if (tid == 0) sh_base = atomicAdd(gCursor, T);
    __syncthreads();
    const int base = sh_base;

    if (tid < nn) {
        int c = cnt[tid];
        int excl = sc[tid] - c;
        rs[n0 + tid] = base + excl;
        ce[n0 + tid] = base + sc[tid];
        dinv[n0 + tid] = rsqrtf((float)(c + 1));   // +1 self-loop
        sc[tid] = excl;
    }
    cnt[tid] = 0;
    __syncthreads();

    for (int idx = tid; idx < cntB; idx += 512) {
        unsigned p = bk[idx];
        int l = (int)(p >> 17);
        int ofs = atomicAdd(&cnt[l], 1);
        csr[base + sc[l] + ofs] = (int)(p & 0x1FFFFu);
    }
}

// ---------------- fp16 scaled-accumulate helpers ----------------
__device__ __forceinline__ void acc8s(float a[8], uint4 u, float s) {
    __half2 h0 = *(__half2*)&u.x, h1 = *(__half2*)&u.y;
    __half2 h2 = *(__half2*)&u.z, h3 = *(__half2*)&u.w;
    float2 f0 = __half22float2(h0), f1 = __half22float2(h1);
    float2 f2 = __half22float2(h2), f3 = __half22float2(h3);
    a[0] = fmaf(s, f0.x, a[0]); a[1] = fmaf(s, f0.y, a[1]);
    a[2] = fmaf(s, f1.x, a[2]); a[3] = fmaf(s, f1.y, a[3]);
    a[4] = fmaf(s, f2.x, a[4]); a[5] = fmaf(s, f2.y, a[5]);
    a[6] = fmaf(s, f3.x, a[6]); a[7] = fmaf(s, f3.y, a[7]);
}

__device__ __forceinline__ void acc4(float a[4], uint2 u) {
    __half2 h0 = *(__half2*)&u.x, h1 = *(__half2*)&u.y;
    float2 f0 = __half22float2(h0), f1 = __half22float2(h1);
    a[0] += f0.x; a[1] += f0.y; a[2] += f1.x; a[3] += f1.y;
}

// ---------------- fused gather1 + GEMM2 ----------------
// 512 thr, 64 nodes/block. Phase 1: 8 lanes/node gather raw-h messages scaled
// by dinv[src]; a1 = relu(dinv_i*acc + b1) -> LDS. Phase 2: MFMA a1 @ W2^T,
// epilogue scales by dinv[row] -> hs2 (fp16). a1 never touches HBM.
__global__ __launch_bounds__(512) void k_fuse(const int* __restrict__ rs,
                                              const int* __restrict__ ce,
                                              const int* __restrict__ csr,
                                              const _Float16* __restrict__ hs,
                                              const float* __restrict__ dinv,
                                              const float* __restrict__ b1,
                                              const _Float16* __restrict__ w2t,
                                              _Float16* __restrict__ hs2) {
    __shared__ _Float16 al[64][72];    // 9.2 KB (+8 pad)
    __shared__ _Float16 wl2[48][72];   // 6.9 KB
    const int tid = threadIdx.x;
    const int row0 = blockIdx.x * 64;

    if (tid < 384)   // stage W2^T: 384 uint4 (consumed after the barrier)
        *(uint4*)&wl2[tid >> 3][(tid & 7) * 8] = ((const uint4*)w2t)[tid];

    // ---- phase 1: gather ----
    {
        int r = tid >> 3, g = tid & 7;
        int i = row0 + r; if (i >= NN) i = NN - 1;   // dup rows; writes guarded later
        const __half* hsh = (const __half*)hs;
        float dvi = dinv[i];
        float acc[8] = {0, 0, 0, 0, 0, 0, 0, 0};
        acc8s(acc, *(const uint4*)&hsh[(size_t)i * F1 + g * 8], dvi);  // self-loop
        int k = rs[i], end = ce[i];
        for (; k + 4 <= end; k += 4) {
            int s0 = csr[k], s1 = csr[k + 1], s2 = csr[k + 2], s3 = csr[k + 3];
            float d0 = dinv[s0], d1 = dinv[s1], d2 = dinv[s2], d3 = dinv[s3];
            uint4 u0 = *(const uint4*)&hsh[(size_t)s0 * F1 + g * 8];
            uint4 u1 = *(const uint4*)&hsh[(size_t)s1 * F1 + g * 8];
            uint4 u2 = *(const uint4*)&hsh[(size_t)s2 * F1 + g * 8];
            uint4 u3 = *(const uint4*)&hsh[(size_t)s3 * F1 + g * 8];
            acc8s(acc, u0, d0); acc8s(acc, u1, d1);
            acc8s(acc, u2, d2); acc8s(acc, u3, d3);
        }
        for (; k < end; ++k) {
            int s0 = csr[k];
            acc8s(acc, *(const uint4*)&hsh[(size_t)s0 * F1 + g * 8], dinv[s0]);
        }
        float4 c0 = *(const float4*)&b1[g * 8];
        float4 c1 = *(const float4*)&b1[g * 8 + 4];
        f16x8 o;
        o[0] = (_Float16)fmaxf(fmaf(dvi, acc[0], c0.x), 0.0f);
        o[1] = (_Float16)fmaxf(fmaf(dvi, acc[1], c0.y), 0.0f);
        o[2] = (_Float16)fmaxf(fmaf(dvi, acc[2], c0.z), 0.0f);
        o[3] = (_Float16)fmaxf(fmaf(dvi, acc[3], c0.w), 0.0f);
        o[4] = (_Float16)fmaxf(fmaf(dvi, acc[4], c1.x), 0.0f);
        o[5] = (_Float16)fmaxf(fmaf(dvi, acc[5], c1.y), 0.0f);
        o[6] = (_Float16)fmaxf(fmaf(dvi, acc[6], c1.z), 0.0f);
        o[7] = (_Float16)fmaxf(fmaf(dvi, acc[7], c1.w), 0.0f);
        *(f16x8*)&al[r][g * 8] = o;
    }
    __syncthreads();

    // ---- phase 2: MFMA a1 @ W2^T ----
    const int wave = tid >> 6;
    const int lane = tid & 63;
    const int l16 = lane & 15;
    const int g8 = (lane >> 4) * 8;

    for (int t = wave; t < 12; t += 8) {   // 12 tiles: 4 row x 3 col
        int rt = t / 3, ct = t - rt * 3;
        f32x4 acc = {0, 0, 0, 0};
        #pragma unroll
        for (int k0 = 0; k0 < F1; k0 += 32) {
            f16x8 a = *(f16x8*)&al[rt * 16 + l16][k0 + g8];
            f16x8 b = *(f16x8*)&wl2[ct * 16 + l16][k0 + g8];
            acc = __builtin_amdgcn_mfma_f32_16x16x32_f16(a, b, acc, 0, 0, 0);
        }
        int col = ct * 16 + l16;
        int baserow = row0 + rt * 16 + (lane >> 4) * 4;
        if (col < F2) {
            #pragma unroll
            for (int j = 0; j < 4; ++j) {
                int gr = baserow + j;
                if (gr < NN)
                    hs2[(size_t)gr * F2 + col] = (_Float16)(acc[j] * dinv[gr]);
            }
        }
    }
}

// ---------------- gather2: out = dinv*(hs2[i] + sum_nbr hs2[s]) + b2 ----------------
// 10 lanes per node, 4 halfs (8 B) per lane; 320-thread blocks, grid 3125 exact
__global__ __launch_bounds__(320) void k_gather2(const int* __restrict__ rs,
                                                 const int* __restrict__ ce,
                                                 const int* __restrict__ csr,
                                                 const __half* __restrict__ hs2,
                                                 const float* __restrict__ dinv,
                                                 const float* __restrict__ b,
                                                 float* __restrict__ outp) {
    int t = blockIdx.x * 320 + threadIdx.x;   // t < 1,000,000 exact
    int i = t / 10;
    int g = t - i * 10;
    float acc[4] = {0, 0, 0, 0};
    acc4(acc, *(const uint2*)&hs2[(size_t)i * F2 + g * 4]);   // self-loop
    int k = rs[i], end = ce[i];
    for (; k + 4 <= end; k += 4) {
        int s0 = csr[k], s1 = csr[k + 1], s2 = csr[k + 2], s3 = csr[k + 3];
        uint2 u0 = *(const uint2*)&hs2[(size_t)s0 * F2 + g * 4];
        uint2 u1 = *(const uint2*)&hs2[(size_t)s1 * F2 + g * 4];
        uint2 u2 = *(const uint2*)&hs2[(size_t)s2 * F2 + g * 4];
        uint2 u3 = *(const uint2*)&hs2[(size_t)s3 * F2 + g * 4];
        acc4(acc, u0); acc4(acc, u1); acc4(acc, u2); acc4(acc, u3);
    }
    for (; k < end; ++k)
        acc4(acc, *(const uint2*)&hs2[(size_t)csr[k] * F2 + g * 4]);

    float dv = dinv[i];
    float4 bb = *(const float4*)&b[g * 4];
    float4 r;
    r.x = fmaf(dv, acc[0], bb.x);
    r.y = fmaf(dv, acc[1], bb.y);
    r.z = fmaf(dv, acc[2], bb.z);
    r.w = fmaf(dv, acc[3], bb.w);
    *(float4*)&outp[(size_t)i * F2 + g * 4] = r;
}

extern "C" void kernel_launch(void* const* d_in, const int* in_sizes, int n_in,
                              void* d_out, int out_size, void* d_ws, size_t ws_size,
                              hipStream_t stream) {
    const float* x  = (const float*)d_in[0];
    const int*   ei = (const int*)d_in[1];
    const float* W1 = (const float*)d_in[2];
    const float* b1 = (const float*)d_in[3];
    const float* W2 = (const float*)d_in[4];
    const float* b2 = (const float*)d_in[5];
    float* out = (float*)d_out;

    const int* src = ei;
    const int* dst = ei + NE;

    // workspace layout in 4-byte units (~29 MB):
    // [dinv 102400][rs 102400][ce 102400][bucketCnt 1024][w1t 4096][w2t 1536]
    // [csr 1.6M][hs 3.2M (NN*64 fp16)][bucket 2.1M (8.4 MB)]
    // hs2 (NN*40 fp16 = 8 MB) aliases bucket (consumed by k_build first).
    float*    dinv      = (float*)d_ws;
    int*      rs        = (int*)d_ws + 102400;
    int*      ce        = (int*)d_ws + 204800;
    int*      bucketCnt = (int*)d_ws + 307200;    // [0..255]=counts, [256]=gCursor
    _Float16* w1t       = (_Float16*)((int*)d_ws + 308224);  // 8192 halfs
    _Float16* w2t       = (_Float16*)((int*)d_ws + 312320);  // 3072 halfs
    int*      csr       = (int*)d_ws + 313856;
    _Float16* hs        = (_Float16*)((int*)d_ws + 313856 + NE);   // NN*64 fp16
    unsigned* bucket    = (unsigned*)((int*)d_ws + 313856 + NE + 3200000);
    _Float16* hs2       = (_Float16*)bucket;

    // 1: zero counters + fp16 transposed weights
    k_init<<<44, 256, 0, stream>>>(W1, W2, w1t, w2t, bucketCnt);
    // 2: gemm1 (raw h) || edge partition — independent work, one launch
    k_g1p<<<GEMM1_BLOCKS + PART_BLOCKS, 256, 0, stream>>>(x, w1t, src, dst,
                                                          bucketCnt, bucket, hs);
    // 3: CSR segments + dinv
    k_build<<<NB, 512, 0, stream>>>(bucketCnt, bucket, bucketCnt + NB,
                                    rs, ce, csr, dinv);
    // 4: gather1 (+dinv[src] scaling) fused with gemm2
    k_fuse<<<GEMM1_BLOCKS, 512, 0, stream>>>(rs, ce, csr, hs, dinv, b1, w2t, hs2);
    // 5: gather2 -> out
    k_gather2<<<NN / 32, 320, 0, stream>>>(rs, ce, csr, (const __half*)hs2,
                                           dinv, b2, out);
}